// Round 6
// baseline (446.337 us; speedup 1.0000x reference)
//
#include <hip/hip_runtime.h>

#define N_NODES 100000
#define N_EDGES 1600000
#define N_GRAPHS 128
#define FDIM 64
#define EPSV 1e-5f
#define NEG 0.01f

#define NB 782              // ceil(N_NODES/128) dst-range buckets
#define PART_BLOCKS 391     // ceil(N_EDGES/4096)

__device__ __forceinline__ float leaky(float x){ return x >= 0.f ? x : NEG*x; }
__device__ __forceinline__ float bcastf(float v, int k){
    return __uint_as_float((unsigned)__builtin_amdgcn_readlane(__float_as_uint(v), k));
}

// ================= bucket histogram (782 bins, LDS-reduced) =================
__global__ __launch_bounds__(256) void k_bh(const int* __restrict__ dst, int* __restrict__ bhist){
    __shared__ int lh[NB];
    int t = threadIdx.x;
    for (int i = t; i < NB; i += 256) lh[i] = 0;
    __syncthreads();
    int base = blockIdx.x * 4096;
    #pragma unroll
    for (int k = 0; k < 16; ++k){
        int e = base + k*256 + t;
        if (e < N_EDGES) atomicAdd(&lh[dst[e] >> 7], 1);
    }
    __syncthreads();
    for (int i = t; i < NB; i += 256) if (lh[i]) atomicAdd(&bhist[i], lh[i]);
}

// ================= single-block exclusive scan of NB bucket sizes =================
__global__ __launch_bounds__(256) void k_bscan(const int* __restrict__ bhist,
                                               int* __restrict__ boff, int* __restrict__ cur){
    __shared__ int lds[256];
    int t = threadIdx.x;
    int base = t*4;
    int v0 = (base+0 < NB) ? bhist[base+0] : 0;
    int v1 = (base+1 < NB) ? bhist[base+1] : 0;
    int v2 = (base+2 < NB) ? bhist[base+2] : 0;
    int v3 = (base+3 < NB) ? bhist[base+3] : 0;
    lds[t] = v0+v1+v2+v3; __syncthreads();
    for (int off = 1; off < 256; off <<= 1){
        int add = (t >= off) ? lds[t-off] : 0; __syncthreads();
        lds[t] += add; __syncthreads();
    }
    int excl = (t > 0) ? lds[t-1] : 0;
    int p0 = excl, p1 = excl+v0, p2 = excl+v0+v1, p3 = excl+v0+v1+v2;
    if (base+0 < NB){ boff[base+0] = p0; cur[base+0] = p0; }
    if (base+1 < NB){ boff[base+1] = p1; cur[base+1] = p1; }
    if (base+2 < NB){ boff[base+2] = p2; cur[base+2] = p2; }
    if (base+3 < NB){ boff[base+3] = p3; cur[base+3] = p3; }
    if (t == 0) boff[NB] = N_EDGES;
}

// ================= partition edges into dst buckets, packed (src<<7)|dst_local =================
__global__ __launch_bounds__(256) void k_part(const int* __restrict__ src, const int* __restrict__ dst,
                                              int* __restrict__ cur, int* __restrict__ packed){
    __shared__ int lh[NB];
    __shared__ int lc[NB];
    int t = threadIdx.x;
    for (int i = t; i < NB; i += 256) lh[i] = 0;
    __syncthreads();
    int base = blockIdx.x * 4096;
    int d[16];
    #pragma unroll
    for (int k = 0; k < 16; ++k){
        int e = base + k*256 + t;
        d[k] = (e < N_EDGES) ? dst[e] : -1;
        if (d[k] >= 0) atomicAdd(&lh[d[k] >> 7], 1);
    }
    __syncthreads();
    for (int i = t; i < NB; i += 256) lc[i] = atomicAdd(&cur[i], lh[i]);
    __syncthreads();
    #pragma unroll
    for (int k = 0; k < 16; ++k){
        int e = base + k*256 + t;
        if (e < N_EDGES){
            int b = d[k] >> 7;
            int p = atomicAdd(&lc[b], 1);
            packed[p] = (src[e] << 7) | (d[k] & 127);
        }
    }
}

// ======== per-bucket counting sort: packed bucket -> CSR (rs + col), coalesced region ========
__global__ __launch_bounds__(256) void k_sort(const int* __restrict__ packed,
                                              const int* __restrict__ boff,
                                              int* __restrict__ rs, int* __restrict__ col){
    __shared__ int hist[128];
    __shared__ int curs[128];
    int b = blockIdx.x, t = threadIdx.x;
    int e0 = boff[b], e1 = boff[b+1];
    if (t < 128) hist[t] = 0;
    __syncthreads();
    for (int e = e0 + t; e < e1; e += 256)
        atomicAdd(&hist[packed[e] & 127], 1);
    __syncthreads();
    int cnt = (t < 128) ? hist[t] : 0;
    __syncthreads();
    for (int off = 1; off < 128; off <<= 1){
        int add = (t < 128 && t >= off) ? hist[t-off] : 0;
        __syncthreads();
        if (t < 128) hist[t] += add;
        __syncthreads();
    }
    int nbase = b << 7;
    int nloc = min(128, N_NODES - nbase);
    if (t < nloc){
        int excl = hist[t] - cnt;          // exclusive scan
        rs[nbase + t] = e0 + excl;
        curs[t] = excl;
    }
    __syncthreads();
    for (int e = e0 + t; e < e1; e += 256){
        int v = packed[e];
        int p = atomicAdd(&curs[v & 127], 1);
        col[e0 + p] = ((unsigned)v) >> 7;
    }
    if (b == 0 && t == 0) rs[N_NODES] = N_EDGES;
}

// ============ pure gather-mean: wave per node, 16 lanes x float4, 4 edges/instr ============
__global__ __launch_bounds__(256) void k_agg(
    const float* __restrict__ xin, const int* __restrict__ rs, const int* __restrict__ col,
    float* __restrict__ agg)
{
    int t = threadIdx.x;
    int lane = t & 63;
    int sub = lane >> 4;          // edge slot 0..3
    int q   = lane & 15;          // feature quad
    int wid = (blockIdx.x << 2) + (t >> 6);
    const int nw = gridDim.x << 2;
    for (int n = wid; n < N_NODES; n += nw){
        int e0 = __builtin_amdgcn_readfirstlane(rs[n]);
        int e1 = __builtin_amdgcn_readfirstlane(rs[n+1]);
        float ax=0.f, ay=0.f, az=0.f, aw=0.f;
        for (int e = e0; e < e1; e += 8){
            int i0 = e + sub, i1 = e + 4 + sub;
            if (i0 < e1){
                const float4* row = (const float4*)(xin + ((size_t)col[i0] << 6));
                float4 v = row[q];
                ax += v.x; ay += v.y; az += v.z; aw += v.w;
            }
            if (i1 < e1){
                const float4* row = (const float4*)(xin + ((size_t)col[i1] << 6));
                float4 v = row[q];
                ax += v.x; ay += v.y; az += v.z; aw += v.w;
            }
        }
        ax += __shfl_xor(ax, 16, 64); ay += __shfl_xor(ay, 16, 64);
        az += __shfl_xor(az, 16, 64); aw += __shfl_xor(aw, 16, 64);
        ax += __shfl_xor(ax, 32, 64); ay += __shfl_xor(ay, 32, 64);
        az += __shfl_xor(az, 32, 64); aw += __shfl_xor(aw, 32, 64);
        if (sub == 0){
            float rd = 1.f / fmaxf((float)(e1 - e0), 1.f);
            float4 o = make_float4(ax*rd, ay*rd, az*rd, aw*rd);
            ((float4*)(agg + ((size_t)n << 6)))[q] = o;
        }
    }
}

// ============ streaming dual-GEMM + leaky + BN partials; affine folded into weights ============
// 32 KiB LDS exactly (5 blocks/CU); M=8 nodes/wave; next-chunk A/X prefetch.
template<bool AFF>
__global__ __launch_bounds__(256, 5) void k_gemm(
    float* aggh, const float* __restrict__ xin,
    const int* __restrict__ rs,
    const float* __restrict__ Wl, const float* __restrict__ bl,
    const float* __restrict__ Wr,
    const float* __restrict__ scale, const float* __restrict__ shift,
    float* __restrict__ bnsum, float* __restrict__ bnsq)
{
    __shared__ float sW[8192];          // [0,4096)=Wl*sc, [4096,8192)=Wr*sc; reused for BN red.
    int t = threadIdx.x;
    int lane = t & 63;
    for (int i = t; i < 4096; i += 256){
        float s = AFF ? scale[i >> 6] : 1.f;
        sW[i]        = Wl[i] * s;
        sW[4096 + i] = Wr[i] * s;
    }
    float bb = bl[lane], bd = 0.f;
    if (AFF){
        #pragma unroll 8
        for (int k = 0; k < 64; ++k){
            float sh = shift[k];
            bb += sh * Wr[(k<<6) + lane];
            bd += sh * Wl[(k<<6) + lane];
        }
    }
    __syncthreads();
    float bs = 0.f, bq = 0.f;
    const int NQ = N_NODES >> 3;        // 12500
    int wid = (blockIdx.x << 2) + (t >> 6);
    int nw = gridDim.x << 2;

    float aA[8], aX[8];
    int c = wid;
    if (c < NQ){
        int n0 = c << 3;
        #pragma unroll
        for (int m = 0; m < 8; ++m){
            aA[m] = aggh[((size_t)(n0+m) << 6) + lane];
            aX[m] = xin [((size_t)(n0+m) << 6) + lane];
        }
    }
    while (c < NQ){
        int n0 = c << 3;
        int c2 = c + nw;
        float bA[8], bX[8];
        if (c2 < NQ){                    // prefetch next chunk under the FMA loop
            int n1 = c2 << 3;
            #pragma unroll
            for (int m = 0; m < 8; ++m){
                bA[m] = aggh[((size_t)(n1+m) << 6) + lane];
                bX[m] = xin [((size_t)(n1+m) << 6) + lane];
            }
        }
        float acc[8];
        #pragma unroll
        for (int m = 0; m < 8; ++m){
            if (AFF) acc[m] = bb + ((rs[n0+m+1] - rs[n0+m]) > 0 ? bd : 0.f);
            else     acc[m] = bb;
        }
        #pragma unroll 8
        for (int k = 0; k < 64; ++k){
            float wl = sW[(k<<6) + lane];
            float wr = sW[4096 + (k<<6) + lane];
            #pragma unroll
            for (int m = 0; m < 8; ++m)
                acc[m] += bcastf(aA[m], k)*wl + bcastf(aX[m], k)*wr;
        }
        #pragma unroll
        for (int m = 0; m < 8; ++m){
            float h = leaky(acc[m]);
            aggh[((size_t)(n0+m) << 6) + lane] = h;
            bs += h; bq += h*h;
        }
        #pragma unroll
        for (int m = 0; m < 8; ++m){ aA[m] = bA[m]; aX[m] = bX[m]; }
        c = c2;
    }
    __syncthreads();                     // weights no longer needed: reuse sW as scratch
    sW[t] = bs; __syncthreads();
    if (t < 64) atomicAdd(&bnsum[t], sW[t]+sW[t+64]+sW[t+128]+sW[t+192]);
    __syncthreads();
    sW[t] = bq; __syncthreads();
    if (t < 64) atomicAdd(&bnsq[t],  sW[t]+sW[t+64]+sW[t+128]+sW[t+192]);
}

// ============ BN finalize ============
__global__ void k_bnfin(const float* __restrict__ sum, const float* __restrict__ sumsq,
                        const float* __restrict__ gamma, const float* __restrict__ beta,
                        float* __restrict__ scale, float* __restrict__ shift){
    int j = threadIdx.x;
    if (j < FDIM){
        float mu  = sum[j]   * (1.0f/N_NODES);
        float var = sumsq[j] * (1.0f/N_NODES) - mu*mu;
        float sc  = gamma[j] * rsqrtf(var + EPSV);
        scale[j] = sc;
        shift[j] = beta[j] - mu*sc;
    }
}

// ============ pooling: sorted batch -> segmented reduction ============
__global__ __launch_bounds__(256) void k_pool2(
    const float* __restrict__ h, const int* __restrict__ batch,
    const float* __restrict__ scale, const float* __restrict__ shift,
    float* __restrict__ pooled)
{
    __shared__ int seg[2];
    __shared__ float red[256];
    int g = blockIdx.x, t = threadIdx.x, j = t & 63, slot = t >> 6;
    if (t < 2){
        int target = g + t;
        int lo = 0, hi = N_NODES;
        while (lo < hi){ int mid = (lo+hi)>>1; if (batch[mid] < target) lo = mid+1; else hi = mid; }
        seg[t] = lo;
    }
    __syncthreads();
    int start = seg[0], end = seg[1];
    float acc = 0.f;
    for (int n = start + slot; n < end; n += 4)
        acc += h[(long long)n*FDIM + j];
    red[t] = acc; __syncthreads();
    if (t < 64){
        float s = red[t]+red[t+64]+red[t+128]+red[t+192];
        float c = fmaxf((float)(end - start), 1.f);
        pooled[g*FDIM + t] = (end > start) ? (s/c)*scale[t] + shift[t] : 0.f;
    }
}

// ============ final MLP ============
__global__ __launch_bounds__(256) void k_mlp(
    const float* __restrict__ pooled, const float* __restrict__ gf,
    const float* __restrict__ Wm0, const float* __restrict__ bm0,
    const float* __restrict__ Wm1, const float* __restrict__ bm1,
    const float* __restrict__ Wm2, const float* __restrict__ bm2,
    float* __restrict__ out)
{
    __shared__ float z[128];
    __shared__ float h1[256];
    __shared__ float h2[128];
    int g = blockIdx.x, t = threadIdx.x;
    if (t < 64)       z[t] = pooled[g*FDIM + t];
    else if (t < 128) z[t] = gf[g*FDIM + (t-64)];
    __syncthreads();
    float acc = bm0[t];
    #pragma unroll 8
    for (int k = 0; k < 128; ++k) acc += z[k]*Wm0[k*256 + t];
    h1[t] = leaky(acc);
    __syncthreads();
    if (t < 128){
        float a = bm1[t];
        #pragma unroll 8
        for (int k = 0; k < 256; ++k) a += h1[k]*Wm1[k*128 + t];
        h2[t] = leaky(a);
    }
    __syncthreads();
    if (t < 2){
        float a = bm2[t];
        for (int k = 0; k < 128; ++k) a += h2[k]*Wm2[k*2 + t];
        out[g*2 + t] = a;
    }
}

extern "C" void kernel_launch(void* const* d_in, const int* in_sizes, int n_in,
                              void* d_out, int out_size, void* d_ws, size_t ws_size,
                              hipStream_t stream) {
    const float* x     = (const float*)d_in[0];
    const int*   ei    = (const int*)d_in[1];
    const float* gf    = (const float*)d_in[2];
    const int*   batch = (const int*)d_in[3];
    const float* Wl0 = (const float*)d_in[4];
    const float* bl0 = (const float*)d_in[5];
    const float* Wr0 = (const float*)d_in[6];
    const float* g0  = (const float*)d_in[7];
    const float* b0  = (const float*)d_in[8];
    const float* Wl1 = (const float*)d_in[9];
    const float* bl1 = (const float*)d_in[10];
    const float* Wr1 = (const float*)d_in[11];
    const float* g1  = (const float*)d_in[12];
    const float* b1  = (const float*)d_in[13];
    const float* Wm0 = (const float*)d_in[14];
    const float* bm0 = (const float*)d_in[15];
    const float* Wm1 = (const float*)d_in[16];
    const float* bm1 = (const float*)d_in[17];
    const float* Wm2 = (const float*)d_in[18];
    const float* bm2 = (const float*)d_in[19];

    // ---- workspace ----
    int*   bhist  = (int*)d_ws;                      // [NB]
    int*   boff   = bhist + NB;                      // [NB+1]
    int*   cur    = boff + NB + 1;                   // [NB]   (total 2347 -> pad 2348)
    int*   packed = (int*)d_ws + 2348;               // [E]
    int*   rs     = packed + N_EDGES;                // [N+1]  (pad to 100004)
    int*   col    = rs + 100004;                     // [E]
    float* bufA   = (float*)(col + N_EDGES);         // [N,64] agg1 -> h1 (in-place)
    float* bufB   = bufA + (size_t)N_NODES*FDIM;     // [N,64] agg2 -> h2 (in-place)
    float* bnsum  = bufB + (size_t)N_NODES*FDIM;     // [64]
    float* bnsq   = bnsum + 64;
    float* scale0 = bnsum + 128;
    float* shift0 = bnsum + 192;
    float* scale1 = bnsum + 256;
    float* shift1 = bnsum + 320;
    float* pooled = bnsum + 384;                     // [128,64]

    const int* srcp = ei;
    const int* dstp = ei + N_EDGES;

    // ---- bucketed CSR build ----
    hipMemsetAsync(bhist, 0, NB*sizeof(int), stream);
    k_bh<<<PART_BLOCKS, 256, 0, stream>>>(dstp, bhist);
    k_bscan<<<1, 256, 0, stream>>>(bhist, boff, cur);
    k_part<<<PART_BLOCKS, 256, 0, stream>>>(srcp, dstp, cur, packed);
    k_sort<<<NB, 256, 0, stream>>>(packed, boff, rs, col);

    // ---- layer 1 ----
    hipMemsetAsync(bnsum, 0, 128*sizeof(float), stream);
    k_agg<<<2048, 256, 0, stream>>>(x, rs, col, bufA);
    k_gemm<false><<<1280, 256, 0, stream>>>(bufA, x, rs, Wl0, bl0, Wr0,
                                            nullptr, nullptr, bnsum, bnsq);
    k_bnfin<<<1, 64, 0, stream>>>(bnsum, bnsq, g0, b0, scale0, shift0);

    // ---- layer 2 ----
    hipMemsetAsync(bnsum, 0, 128*sizeof(float), stream);
    k_agg<<<2048, 256, 0, stream>>>(bufA, rs, col, bufB);
    k_gemm<true><<<1280, 256, 0, stream>>>(bufB, bufA, rs, Wl1, bl1, Wr1,
                                           scale0, shift0, bnsum, bnsq);
    k_bnfin<<<1, 64, 0, stream>>>(bnsum, bnsq, g1, b1, scale1, shift1);

    // ---- pooling + MLP ----
    k_pool2<<<N_GRAPHS, 256, 0, stream>>>(bufB, batch, scale1, shift1, pooled);
    k_mlp<<<N_GRAPHS, 256, 0, stream>>>(pooled, gf, Wm0, bm0, Wm1, bm1, Wm2, bm2, (float*)d_out);
}

// Round 7
// 423.203 us; speedup vs baseline: 1.0547x; 1.0547x over previous
//
#include <hip/hip_runtime.h>

#define N_NODES 100000
#define N_EDGES 1600000
#define N_GRAPHS 128
#define FDIM 64
#define EPSV 1e-5f
#define NEG 0.01f

#define NB 782              // ceil(N_NODES/128) dst-range buckets
#define PART_BLOCKS 391     // ceil(N_EDGES/4096)
#define NTILES 6250         // N_NODES/16 (exact)
#define GEMM_BLOCKS 1563    // ceil(NTILES/4)

typedef short bf16x8 __attribute__((ext_vector_type(8)));
typedef float f32x4  __attribute__((ext_vector_type(4)));

__device__ __forceinline__ float leaky(float x){ return x >= 0.f ? x : NEG*x; }

__device__ __forceinline__ unsigned short f2bf(float x){
    unsigned u = __float_as_uint(x);
    return (unsigned short)((u + 0x7fffu + ((u >> 16) & 1u)) >> 16);   // RN-even
}
__device__ __forceinline__ float bf2f(unsigned short b){
    return __uint_as_float(((unsigned)b) << 16);
}
__device__ __forceinline__ void split8(const float4& v0, const float4& v1,
                                       bf16x8& hi, bf16x8& lo){
    float f[8] = {v0.x, v0.y, v0.z, v0.w, v1.x, v1.y, v1.z, v1.w};
    #pragma unroll
    for (int i = 0; i < 8; ++i){
        unsigned short h = f2bf(f[i]);
        hi[i] = (short)h;
        lo[i] = (short)f2bf(f[i] - bf2f(h));
    }
}

// ================= bucket histogram (782 bins, LDS-reduced) =================
__global__ __launch_bounds__(256) void k_bh(const int* __restrict__ dst, int* __restrict__ bhist){
    __shared__ int lh[NB];
    int t = threadIdx.x;
    for (int i = t; i < NB; i += 256) lh[i] = 0;
    __syncthreads();
    int base = blockIdx.x * 4096;
    #pragma unroll
    for (int k = 0; k < 16; ++k){
        int e = base + k*256 + t;
        if (e < N_EDGES) atomicAdd(&lh[dst[e] >> 7], 1);
    }
    __syncthreads();
    for (int i = t; i < NB; i += 256) if (lh[i]) atomicAdd(&bhist[i], lh[i]);
}

// ================= single-block exclusive scan of NB bucket sizes =================
__global__ __launch_bounds__(256) void k_bscan(const int* __restrict__ bhist,
                                               int* __restrict__ boff, int* __restrict__ cur){
    __shared__ int lds[256];
    int t = threadIdx.x;
    int base = t*4;
    int v0 = (base+0 < NB) ? bhist[base+0] : 0;
    int v1 = (base+1 < NB) ? bhist[base+1] : 0;
    int v2 = (base+2 < NB) ? bhist[base+2] : 0;
    int v3 = (base+3 < NB) ? bhist[base+3] : 0;
    lds[t] = v0+v1+v2+v3; __syncthreads();
    for (int off = 1; off < 256; off <<= 1){
        int add = (t >= off) ? lds[t-off] : 0; __syncthreads();
        lds[t] += add; __syncthreads();
    }
    int excl = (t > 0) ? lds[t-1] : 0;
    int p0 = excl, p1 = excl+v0, p2 = excl+v0+v1, p3 = excl+v0+v1+v2;
    if (base+0 < NB){ boff[base+0] = p0; cur[base+0] = p0; }
    if (base+1 < NB){ boff[base+1] = p1; cur[base+1] = p1; }
    if (base+2 < NB){ boff[base+2] = p2; cur[base+2] = p2; }
    if (base+3 < NB){ boff[base+3] = p3; cur[base+3] = p3; }
    if (t == 0) boff[NB] = N_EDGES;
}

// ================= partition edges into dst buckets, packed (src<<7)|dst_local =================
__global__ __launch_bounds__(256) void k_part(const int* __restrict__ src, const int* __restrict__ dst,
                                              int* __restrict__ cur, int* __restrict__ packed){
    __shared__ int lh[NB];
    __shared__ int lc[NB];
    int t = threadIdx.x;
    for (int i = t; i < NB; i += 256) lh[i] = 0;
    __syncthreads();
    int base = blockIdx.x * 4096;
    int d[16];
    #pragma unroll
    for (int k = 0; k < 16; ++k){
        int e = base + k*256 + t;
        d[k] = (e < N_EDGES) ? dst[e] : -1;
        if (d[k] >= 0) atomicAdd(&lh[d[k] >> 7], 1);
    }
    __syncthreads();
    for (int i = t; i < NB; i += 256) lc[i] = atomicAdd(&cur[i], lh[i]);
    __syncthreads();
    #pragma unroll
    for (int k = 0; k < 16; ++k){
        int e = base + k*256 + t;
        if (e < N_EDGES){
            int b = d[k] >> 7;
            int p = atomicAdd(&lc[b], 1);
            packed[p] = (src[e] << 7) | (d[k] & 127);
        }
    }
}

// ======== per-bucket counting sort: packed bucket -> CSR (rs + col), coalesced region ========
__global__ __launch_bounds__(256) void k_sort(const int* __restrict__ packed,
                                              const int* __restrict__ boff,
                                              int* __restrict__ rs, int* __restrict__ col){
    __shared__ int hist[128];
    __shared__ int curs[128];
    int b = blockIdx.x, t = threadIdx.x;
    int e0 = boff[b], e1 = boff[b+1];
    if (t < 128) hist[t] = 0;
    __syncthreads();
    for (int e = e0 + t; e < e1; e += 256)
        atomicAdd(&hist[packed[e] & 127], 1);
    __syncthreads();
    int cnt = (t < 128) ? hist[t] : 0;
    __syncthreads();
    for (int off = 1; off < 128; off <<= 1){
        int add = (t < 128 && t >= off) ? hist[t-off] : 0;
        __syncthreads();
        if (t < 128) hist[t] += add;
        __syncthreads();
    }
    int nbase = b << 7;
    int nloc = min(128, N_NODES - nbase);
    if (t < nloc){
        int excl = hist[t] - cnt;          // exclusive scan
        rs[nbase + t] = e0 + excl;
        curs[t] = excl;
    }
    __syncthreads();
    for (int e = e0 + t; e < e1; e += 256){
        int v = packed[e];
        int p = atomicAdd(&curs[v & 127], 1);
        col[e0 + p] = ((unsigned)v) >> 7;
    }
    if (b == 0 && t == 0) rs[N_NODES] = N_EDGES;
}

// ============ pure gather-mean: wave per node, 16 lanes x float4, 4 edges/instr ============
__global__ __launch_bounds__(256) void k_agg(
    const float* __restrict__ xin, const int* __restrict__ rs, const int* __restrict__ col,
    float* __restrict__ agg)
{
    int t = threadIdx.x;
    int lane = t & 63;
    int sub = lane >> 4;          // edge slot 0..3
    int q   = lane & 15;          // feature quad
    int wid = (blockIdx.x << 2) + (t >> 6);
    const int nw = gridDim.x << 2;
    for (int n = wid; n < N_NODES; n += nw){
        int e0 = __builtin_amdgcn_readfirstlane(rs[n]);
        int e1 = __builtin_amdgcn_readfirstlane(rs[n+1]);
        float ax=0.f, ay=0.f, az=0.f, aw=0.f;
        for (int e = e0; e < e1; e += 8){
            int i0 = e + sub, i1 = e + 4 + sub;
            if (i0 < e1){
                const float4* row = (const float4*)(xin + ((size_t)col[i0] << 6));
                float4 v = row[q];
                ax += v.x; ay += v.y; az += v.z; aw += v.w;
            }
            if (i1 < e1){
                const float4* row = (const float4*)(xin + ((size_t)col[i1] << 6));
                float4 v = row[q];
                ax += v.x; ay += v.y; az += v.z; aw += v.w;
            }
        }
        ax += __shfl_xor(ax, 16, 64); ay += __shfl_xor(ay, 16, 64);
        az += __shfl_xor(az, 16, 64); aw += __shfl_xor(aw, 16, 64);
        ax += __shfl_xor(ax, 32, 64); ay += __shfl_xor(ay, 32, 64);
        az += __shfl_xor(az, 32, 64); aw += __shfl_xor(aw, 32, 64);
        if (sub == 0){
            float rd = 1.f / fmaxf((float)(e1 - e0), 1.f);
            float4 o = make_float4(ax*rd, ay*rd, az*rd, aw*rd);
            ((float4*)(agg + ((size_t)n << 6)))[q] = o;
        }
    }
}

// ============ MFMA dual-GEMM + leaky + BN partials; hi/lo bf16 split for fp32 accuracy ======
// Block = 64 nodes (4 node-tiles). Wave jt owns j-cols [16jt,16jt+16) of all 4 tiles.
// A/X fragments loaded directly from global in MFMA lane layout; h written in-place over aggh
// (per-tile __syncthreads orders all waves' A-frag reads before any wave's write).
template<bool AFF>
__global__ __launch_bounds__(256) void k_gemm(
    float* aggh, const float* __restrict__ xin,
    const int* __restrict__ rs,
    const float* __restrict__ Wl, const float* __restrict__ bl,
    const float* __restrict__ Wr,
    const float* __restrict__ scale, const float* __restrict__ shift,
    float* __restrict__ bnsum, float* __restrict__ bnsq)
{
    int t = threadIdx.x;
    int lane = t & 63;
    int jt = t >> 6;
    int g = lane >> 4, r = lane & 15;
    int j = (jt << 4) + r;

    // ---- W fragments: B[k][j], k = ks*32 + 8g + i, scale folded, hi/lo split ----
    bf16x8 wlh[2], wll[2], wrh[2], wrl[2];
    #pragma unroll
    for (int ks = 0; ks < 2; ++ks){
        #pragma unroll
        for (int i = 0; i < 8; ++i){
            int k = (ks << 5) + (g << 3) + i;
            float s = AFF ? scale[k] : 1.f;
            float wv = Wl[(k << 6) + j] * s;
            unsigned short h = f2bf(wv);
            wlh[ks][i] = (short)h;
            wll[ks][i] = (short)f2bf(wv - bf2f(h));
            wv = Wr[(k << 6) + j] * s;
            h = f2bf(wv);
            wrh[ks][i] = (short)h;
            wrl[ks][i] = (short)f2bf(wv - bf2f(h));
        }
    }

    float bb = bl[j], bd = 0.f;
    if (AFF){
        #pragma unroll 8
        for (int k = 0; k < 64; ++k){
            float sh = shift[k];
            bb += sh * Wr[(k << 6) + j];
            bd += sh * Wl[(k << 6) + j];
        }
    }

    float bs = 0.f, bq = 0.f;
    int base_tile = blockIdx.x << 2;

    #pragma unroll 1
    for (int nt = 0; nt < 4; ++nt){
        int tile = base_tile + nt;
        bool act = (tile < NTILES);          // block-uniform
        bf16x8 ah[2], al[2], xh[2], xl[2];
        if (act){
            size_t rowoff = (((size_t)(tile << 4) + r) << 6) + (g << 3);
            const float4* pa0 = (const float4*)(aggh + rowoff);
            const float4* pa1 = (const float4*)(aggh + rowoff + 32);
            const float4* px0 = (const float4*)(xin + rowoff);
            const float4* px1 = (const float4*)(xin + rowoff + 32);
            float4 a00 = pa0[0], a01 = pa0[1], a10 = pa1[0], a11 = pa1[1];
            float4 x00 = px0[0], x01 = px0[1], x10 = px1[0], x11 = px1[1];
            split8(a00, a01, ah[0], al[0]);
            split8(a10, a11, ah[1], al[1]);
            split8(x00, x01, xh[0], xl[0]);
            split8(x10, x11, xh[1], xl[1]);
        }
        __syncthreads();                     // all A-frag reads of this tile done
        if (act){
            f32x4 accA = {0.f, 0.f, 0.f, 0.f};
            f32x4 accX = {0.f, 0.f, 0.f, 0.f};
            #pragma unroll
            for (int ks = 0; ks < 2; ++ks){
                accA = __builtin_amdgcn_mfma_f32_16x16x32_bf16(ah[ks], wlh[ks], accA, 0, 0, 0);
                accA = __builtin_amdgcn_mfma_f32_16x16x32_bf16(ah[ks], wll[ks], accA, 0, 0, 0);
                accA = __builtin_amdgcn_mfma_f32_16x16x32_bf16(al[ks], wlh[ks], accA, 0, 0, 0);
                accX = __builtin_amdgcn_mfma_f32_16x16x32_bf16(xh[ks], wrh[ks], accX, 0, 0, 0);
                accX = __builtin_amdgcn_mfma_f32_16x16x32_bf16(xh[ks], wrl[ks], accX, 0, 0, 0);
                accX = __builtin_amdgcn_mfma_f32_16x16x32_bf16(xl[ks], wrh[ks], accX, 0, 0, 0);
            }
            #pragma unroll
            for (int q = 0; q < 4; ++q){
                int node = (tile << 4) + (g << 2) + q;   // D row = 4g + q
                float hv = accA[q] + accX[q] + bb;
                if (AFF){ if (rs[node+1] - rs[node] > 0) hv += bd; }
                hv = leaky(hv);
                aggh[((size_t)node << 6) + j] = hv;      // D col = j
                bs += hv; bq += hv*hv;
            }
        }
    }

    // BN partials: lane's j is fixed; reduce over the 4 row-groups sharing each (l&15)
    bs += __shfl_xor(bs, 16, 64); bs += __shfl_xor(bs, 32, 64);
    bq += __shfl_xor(bq, 16, 64); bq += __shfl_xor(bq, 32, 64);
    if (lane < 16){
        atomicAdd(&bnsum[(jt << 4) + lane], bs);
        atomicAdd(&bnsq [(jt << 4) + lane], bq);
    }
}

// ============ BN finalize ============
__global__ void k_bnfin(const float* __restrict__ sum, const float* __restrict__ sumsq,
                        const float* __restrict__ gamma, const float* __restrict__ beta,
                        float* __restrict__ scale, float* __restrict__ shift){
    int j = threadIdx.x;
    if (j < FDIM){
        float mu  = sum[j]   * (1.0f/N_NODES);
        float var = sumsq[j] * (1.0f/N_NODES) - mu*mu;
        float sc  = gamma[j] * rsqrtf(var + EPSV);
        scale[j] = sc;
        shift[j] = beta[j] - mu*sc;
    }
}

// ============ pooling: sorted batch -> segmented reduction ============
__global__ __launch_bounds__(256) void k_pool2(
    const float* __restrict__ h, const int* __restrict__ batch,
    const float* __restrict__ scale, const float* __restrict__ shift,
    float* __restrict__ pooled)
{
    __shared__ int seg[2];
    __shared__ float red[256];
    int g = blockIdx.x, t = threadIdx.x, j = t & 63, slot = t >> 6;
    if (t < 2){
        int target = g + t;
        int lo = 0, hi = N_NODES;
        while (lo < hi){ int mid = (lo+hi)>>1; if (batch[mid] < target) lo = mid+1; else hi = mid; }
        seg[t] = lo;
    }
    __syncthreads();
    int start = seg[0], end = seg[1];
    float acc = 0.f;
    for (int n = start + slot; n < end; n += 4)
        acc += h[(long long)n*FDIM + j];
    red[t] = acc; __syncthreads();
    if (t < 64){
        float s = red[t]+red[t+64]+red[t+128]+red[t+192];
        float c = fmaxf((float)(end - start), 1.f);
        pooled[g*FDIM + t] = (end > start) ? (s/c)*scale[t] + shift[t] : 0.f;
    }
}

// ============ final MLP ============
__global__ __launch_bounds__(256) void k_mlp(
    const float* __restrict__ pooled, const float* __restrict__ gf,
    const float* __restrict__ Wm0, const float* __restrict__ bm0,
    const float* __restrict__ Wm1, const float* __restrict__ bm1,
    const float* __restrict__ Wm2, const float* __restrict__ bm2,
    float* __restrict__ out)
{
    __shared__ float z[128];
    __shared__ float h1[256];
    __shared__ float h2[128];
    int g = blockIdx.x, t = threadIdx.x;
    if (t < 64)       z[t] = pooled[g*FDIM + t];
    else if (t < 128) z[t] = gf[g*FDIM + (t-64)];
    __syncthreads();
    float acc = bm0[t];
    #pragma unroll 8
    for (int k = 0; k < 128; ++k) acc += z[k]*Wm0[k*256 + t];
    h1[t] = leaky(acc);
    __syncthreads();
    if (t < 128){
        float a = bm1[t];
        #pragma unroll 8
        for (int k = 0; k < 256; ++k) a += h1[k]*Wm1[k*128 + t];
        h2[t] = leaky(a);
    }
    __syncthreads();
    if (t < 2){
        float a = bm2[t];
        for (int k = 0; k < 128; ++k) a += h2[k]*Wm2[k*2 + t];
        out[g*2 + t] = a;
    }
}

extern "C" void kernel_launch(void* const* d_in, const int* in_sizes, int n_in,
                              void* d_out, int out_size, void* d_ws, size_t ws_size,
                              hipStream_t stream) {
    const float* x     = (const float*)d_in[0];
    const int*   ei    = (const int*)d_in[1];
    const float* gf    = (const float*)d_in[2];
    const int*   batch = (const int*)d_in[3];
    const float* Wl0 = (const float*)d_in[4];
    const float* bl0 = (const float*)d_in[5];
    const float* Wr0 = (const float*)d_in[6];
    const float* g0  = (const float*)d_in[7];
    const float* b0  = (const float*)d_in[8];
    const float* Wl1 = (const float*)d_in[9];
    const float* bl1 = (const float*)d_in[10];
    const float* Wr1 = (const float*)d_in[11];
    const float* g1  = (const float*)d_in[12];
    const float* b1  = (const float*)d_in[13];
    const float* Wm0 = (const float*)d_in[14];
    const float* bm0 = (const float*)d_in[15];
    const float* Wm1 = (const float*)d_in[16];
    const float* bm1 = (const float*)d_in[17];
    const float* Wm2 = (const float*)d_in[18];
    const float* bm2 = (const float*)d_in[19];

    // ---- workspace ----
    int*   bhist  = (int*)d_ws;                      // [NB]
    int*   boff   = bhist + NB;                      // [NB+1]
    int*   cur    = boff + NB + 1;                   // [NB]   (total 2347 -> pad 2348)
    int*   packed = (int*)d_ws + 2348;               // [E]
    int*   rs     = packed + N_EDGES;                // [N+1]  (pad to 100004)
    int*   col    = rs + 100004;                     // [E]
    float* bufA   = (float*)(col + N_EDGES);         // [N,64] agg1 -> h1 (in-place)
    float* bufB   = bufA + (size_t)N_NODES*FDIM;     // [N,64] agg2 -> h2 (in-place)
    float* bnsum  = bufB + (size_t)N_NODES*FDIM;     // [64]
    float* bnsq   = bnsum + 64;
    float* scale0 = bnsum + 128;
    float* shift0 = bnsum + 192;
    float* scale1 = bnsum + 256;
    float* shift1 = bnsum + 320;
    float* pooled = bnsum + 384;                     // [128,64]

    const int* srcp = ei;
    const int* dstp = ei + N_EDGES;

    // ---- bucketed CSR build ----
    hipMemsetAsync(bhist, 0, NB*sizeof(int), stream);
    k_bh<<<PART_BLOCKS, 256, 0, stream>>>(dstp, bhist);
    k_bscan<<<1, 256, 0, stream>>>(bhist, boff, cur);
    k_part<<<PART_BLOCKS, 256, 0, stream>>>(srcp, dstp, cur, packed);
    k_sort<<<NB, 256, 0, stream>>>(packed, boff, rs, col);

    // ---- layer 1 ----
    hipMemsetAsync(bnsum, 0, 128*sizeof(float), stream);
    k_agg<<<2048, 256, 0, stream>>>(x, rs, col, bufA);
    k_gemm<false><<<GEMM_BLOCKS, 256, 0, stream>>>(bufA, x, rs, Wl0, bl0, Wr0,
                                                   nullptr, nullptr, bnsum, bnsq);
    k_bnfin<<<1, 64, 0, stream>>>(bnsum, bnsq, g0, b0, scale0, shift0);

    // ---- layer 2 ----
    hipMemsetAsync(bnsum, 0, 128*sizeof(float), stream);
    k_agg<<<2048, 256, 0, stream>>>(bufA, rs, col, bufB);
    k_gemm<true><<<GEMM_BLOCKS, 256, 0, stream>>>(bufB, bufA, rs, Wl1, bl1, Wr1,
                                                  scale0, shift0, bnsum, bnsq);
    k_bnfin<<<1, 64, 0, stream>>>(bnsum, bnsq, g1, b1, scale1, shift1);

    // ---- pooling + MLP ----
    k_pool2<<<N_GRAPHS, 256, 0, stream>>>(bufB, batch, scale1, shift1, pooled);
    k_mlp<<<N_GRAPHS, 256, 0, stream>>>(pooled, gf, Wm0, bm0, Wm1, bm1, Wm2, bm2, (float*)d_out);
}

// Round 8
// 350.273 us; speedup vs baseline: 1.2743x; 1.2082x over previous
//
#include <hip/hip_runtime.h>

#define N_NODES 100000
#define N_EDGES 1600000
#define N_GRAPHS 128
#define FDIM 64
#define EPSV 1e-5f
#define NEG 0.01f

#define NB 782              // ceil(N_NODES/128) dst-range buckets
#define PART_BLOCKS 391     // ceil(N_EDGES/4096)
#define NTILES 6250         // N_NODES/16 (exact)
#define GEMM_BLOCKS 1563    // ceil(NTILES/4)

typedef short bf16x8 __attribute__((ext_vector_type(8)));
typedef float f32x4  __attribute__((ext_vector_type(4)));

__device__ __forceinline__ float leaky(float x){ return x >= 0.f ? x : NEG*x; }

// truncation hi/lo split: hi = top 16 bits, lo = exact residual truncated to bf16.
__device__ __forceinline__ void split8(const float4& v0, const float4& v1,
                                       bf16x8& hi, bf16x8& lo){
    float f[8] = {v0.x, v0.y, v0.z, v0.w, v1.x, v1.y, v1.z, v1.w};
    #pragma unroll
    for (int i = 0; i < 8; ++i){
        unsigned u = __float_as_uint(f[i]);
        hi[i] = (short)(u >> 16);
        float lf = f[i] - __uint_as_float(u & 0xffff0000u);   // exact
        lo[i] = (short)(__float_as_uint(lf) >> 16);
    }
}

// ================= bucket histogram (782 bins, LDS-reduced) =================
__global__ __launch_bounds__(256) void k_bh(const int* __restrict__ dst, int* __restrict__ bhist){
    __shared__ int lh[NB];
    int t = threadIdx.x;
    for (int i = t; i < NB; i += 256) lh[i] = 0;
    __syncthreads();
    int base = blockIdx.x * 4096;
    #pragma unroll
    for (int k = 0; k < 16; ++k){
        int e = base + k*256 + t;
        if (e < N_EDGES) atomicAdd(&lh[dst[e] >> 7], 1);
    }
    __syncthreads();
    for (int i = t; i < NB; i += 256) if (lh[i]) atomicAdd(&bhist[i], lh[i]);
}

// ================= single-block exclusive scan of NB bucket sizes =================
__global__ __launch_bounds__(256) void k_bscan(const int* __restrict__ bhist,
                                               int* __restrict__ boff, int* __restrict__ cur){
    __shared__ int lds[256];
    int t = threadIdx.x;
    int base = t*4;
    int v0 = (base+0 < NB) ? bhist[base+0] : 0;
    int v1 = (base+1 < NB) ? bhist[base+1] : 0;
    int v2 = (base+2 < NB) ? bhist[base+2] : 0;
    int v3 = (base+3 < NB) ? bhist[base+3] : 0;
    lds[t] = v0+v1+v2+v3; __syncthreads();
    for (int off = 1; off < 256; off <<= 1){
        int add = (t >= off) ? lds[t-off] : 0; __syncthreads();
        lds[t] += add; __syncthreads();
    }
    int excl = (t > 0) ? lds[t-1] : 0;
    int p0 = excl, p1 = excl+v0, p2 = excl+v0+v1, p3 = excl+v0+v1+v2;
    if (base+0 < NB){ boff[base+0] = p0; cur[base+0] = p0; }
    if (base+1 < NB){ boff[base+1] = p1; cur[base+1] = p1; }
    if (base+2 < NB){ boff[base+2] = p2; cur[base+2] = p2; }
    if (base+3 < NB){ boff[base+3] = p3; cur[base+3] = p3; }
    if (t == 0) boff[NB] = N_EDGES;
}

// ================= partition edges into dst buckets, packed (src<<7)|dst_local =================
__global__ __launch_bounds__(256) void k_part(const int* __restrict__ src, const int* __restrict__ dst,
                                              int* __restrict__ cur, int* __restrict__ packed){
    __shared__ int lh[NB];
    __shared__ int lc[NB];
    int t = threadIdx.x;
    for (int i = t; i < NB; i += 256) lh[i] = 0;
    __syncthreads();
    int base = blockIdx.x * 4096;
    int d[16];
    #pragma unroll
    for (int k = 0; k < 16; ++k){
        int e = base + k*256 + t;
        d[k] = (e < N_EDGES) ? dst[e] : -1;
        if (d[k] >= 0) atomicAdd(&lh[d[k] >> 7], 1);
    }
    __syncthreads();
    for (int i = t; i < NB; i += 256) lc[i] = atomicAdd(&cur[i], lh[i]);
    __syncthreads();
    #pragma unroll
    for (int k = 0; k < 16; ++k){
        int e = base + k*256 + t;
        if (e < N_EDGES){
            int b = d[k] >> 7;
            int p = atomicAdd(&lc[b], 1);
            packed[p] = (src[e] << 7) | (d[k] & 127);
        }
    }
}

// ======== per-bucket counting sort: packed bucket -> CSR (rs + col), coalesced region ========
__global__ __launch_bounds__(256) void k_sort(const int* __restrict__ packed,
                                              const int* __restrict__ boff,
                                              int* __restrict__ rs, int* __restrict__ col){
    __shared__ int hist[128];
    __shared__ int curs[128];
    int b = blockIdx.x, t = threadIdx.x;
    int e0 = boff[b], e1 = boff[b+1];
    if (t < 128) hist[t] = 0;
    __syncthreads();
    for (int e = e0 + t; e < e1; e += 256)
        atomicAdd(&hist[packed[e] & 127], 1);
    __syncthreads();
    int cnt = (t < 128) ? hist[t] : 0;
    __syncthreads();
    for (int off = 1; off < 128; off <<= 1){
        int add = (t < 128 && t >= off) ? hist[t-off] : 0;
        __syncthreads();
        if (t < 128) hist[t] += add;
        __syncthreads();
    }
    int nbase = b << 7;
    int nloc = min(128, N_NODES - nbase);
    if (t < nloc){
        int excl = hist[t] - cnt;          // exclusive scan
        rs[nbase + t] = e0 + excl;
        curs[t] = excl;
    }
    __syncthreads();
    for (int e = e0 + t; e < e1; e += 256){
        int v = packed[e];
        int p = atomicAdd(&curs[v & 127], 1);
        col[e0 + p] = ((unsigned)v) >> 7;
    }
    if (b == 0 && t == 0) rs[N_NODES] = N_EDGES;
}

// ============ pure gather-mean: wave per node, 16 lanes x float4, 4-deep edge unroll ============
__global__ __launch_bounds__(256) void k_agg(
    const float* __restrict__ xin, const int* __restrict__ rs, const int* __restrict__ col,
    float* __restrict__ agg)
{
    int t = threadIdx.x;
    int lane = t & 63;
    int sub = lane >> 4;          // edge slot 0..3
    int q   = lane & 15;          // feature quad
    int wid = (blockIdx.x << 2) + (t >> 6);
    const int nw = gridDim.x << 2;
    for (int n = wid; n < N_NODES; n += nw){
        int e0 = __builtin_amdgcn_readfirstlane(rs[n]);
        int e1 = __builtin_amdgcn_readfirstlane(rs[n+1]);
        float ax=0.f, ay=0.f, az=0.f, aw=0.f;
        for (int e = e0; e < e1; e += 16){
            int i0 = e + sub, i1 = e + 4 + sub, i2 = e + 8 + sub, i3 = e + 12 + sub;
            if (i0 < e1){
                float4 v = ((const float4*)(xin + ((size_t)col[i0] << 6)))[q];
                ax += v.x; ay += v.y; az += v.z; aw += v.w;
            }
            if (i1 < e1){
                float4 v = ((const float4*)(xin + ((size_t)col[i1] << 6)))[q];
                ax += v.x; ay += v.y; az += v.z; aw += v.w;
            }
            if (i2 < e1){
                float4 v = ((const float4*)(xin + ((size_t)col[i2] << 6)))[q];
                ax += v.x; ay += v.y; az += v.z; aw += v.w;
            }
            if (i3 < e1){
                float4 v = ((const float4*)(xin + ((size_t)col[i3] << 6)))[q];
                ax += v.x; ay += v.y; az += v.z; aw += v.w;
            }
        }
        ax += __shfl_xor(ax, 16, 64); ay += __shfl_xor(ay, 16, 64);
        az += __shfl_xor(az, 16, 64); aw += __shfl_xor(aw, 16, 64);
        ax += __shfl_xor(ax, 32, 64); ay += __shfl_xor(ay, 32, 64);
        az += __shfl_xor(az, 32, 64); aw += __shfl_xor(aw, 32, 64);
        if (sub == 0){
            float rd = 1.f / fmaxf((float)(e1 - e0), 1.f);
            float4 o = make_float4(ax*rd, ay*rd, az*rd, aw*rd);
            ((float4*)(agg + ((size_t)n << 6)))[q] = o;
        }
    }
}

// ============ MFMA dual-GEMM, barrier-free, double-buffered tile pipeline ============
template<bool AFF>
__global__ __launch_bounds__(256) void k_gemm(
    const float* __restrict__ agg, const float* __restrict__ xin,
    float* __restrict__ hout,
    const int* __restrict__ rs, const int* __restrict__ batch,
    const float* __restrict__ Wl, const float* __restrict__ bl,
    const float* __restrict__ Wr,
    const float* __restrict__ scale, const float* __restrict__ shift,
    float* __restrict__ bnsum, float* __restrict__ bnsq,
    float* __restrict__ S)
{
    __shared__ float sS[8*64];     // per-block graph-pool bins (AFF only)
    int t = threadIdx.x;
    int lane = t & 63;
    int jt = t >> 6;
    int g = lane >> 4, r = lane & 15;
    int j = (jt << 4) + r;

    bf16x8 wlh[2], wll[2], wrh[2], wrl[2];
    #pragma unroll
    for (int ks = 0; ks < 2; ++ks){
        #pragma unroll
        for (int i = 0; i < 8; ++i){
            int k = (ks << 5) + (g << 3) + i;
            float s = AFF ? scale[k] : 1.f;
            float wv = Wl[(k << 6) + j] * s;
            unsigned u = __float_as_uint(wv);
            wlh[ks][i] = (short)(u >> 16);
            float lf = wv - __uint_as_float(u & 0xffff0000u);
            wll[ks][i] = (short)(__float_as_uint(lf) >> 16);
            wv = Wr[(k << 6) + j] * s;
            u = __float_as_uint(wv);
            wrh[ks][i] = (short)(u >> 16);
            lf = wv - __uint_as_float(u & 0xffff0000u);
            wrl[ks][i] = (short)(__float_as_uint(lf) >> 16);
        }
    }

    float bb = bl[j], bd = 0.f;
    if (AFF){
        #pragma unroll 8
        for (int k = 0; k < 64; ++k){
            float sh = shift[k];
            bb += sh * Wr[(k << 6) + j];
            bd += sh * Wl[(k << 6) + j];
        }
    }

    int gbase = 0, span = 0;
    if (AFF){
        for (int i = t; i < 512; i += 256) sS[i] = 0.f;
        int nfirst = blockIdx.x << 6;
        int nlast  = min(nfirst + 63, N_NODES - 1);
        gbase = batch[nfirst];
        span  = batch[nlast] - gbase + 1;
        __syncthreads();
    }

    float bs = 0.f, bq = 0.f;
    int bt = blockIdx.x << 2;

    auto LOAD = [&](int tile, float4* A, float4* X){
        size_t rowoff = (((size_t)((tile << 4) + r)) << 6) + (g << 3);
        const float4* pa = (const float4*)(agg + rowoff);
        const float4* px = (const float4*)(xin + rowoff);
        A[0] = pa[0]; A[1] = pa[1]; A[2] = pa[8]; A[3] = pa[9];
        X[0] = px[0]; X[1] = px[1]; X[2] = px[8]; X[3] = px[9];
    };

    auto POOL = [&](int gr, float hv){
        int lg = gr - gbase;
        if (lg < 8) atomicAdd(&sS[(lg << 6) + j], hv);
        else        atomicAdd(&S[(gr << 6) + j], hv);
    };

    auto COMPUTE = [&](int tile, const float4* A, const float4* X){
        bf16x8 ah0, al0, ah1, al1, xh0, xl0, xh1, xl1;
        split8(A[0], A[1], ah0, al0);
        split8(A[2], A[3], ah1, al1);
        split8(X[0], X[1], xh0, xl0);
        split8(X[2], X[3], xh1, xl1);
        f32x4 accA = {0.f, 0.f, 0.f, 0.f};
        f32x4 accX = {0.f, 0.f, 0.f, 0.f};
        accA = __builtin_amdgcn_mfma_f32_16x16x32_bf16(ah0, wlh[0], accA, 0, 0, 0);
        accA = __builtin_amdgcn_mfma_f32_16x16x32_bf16(ah0, wll[0], accA, 0, 0, 0);
        accA = __builtin_amdgcn_mfma_f32_16x16x32_bf16(al0, wlh[0], accA, 0, 0, 0);
        accA = __builtin_amdgcn_mfma_f32_16x16x32_bf16(ah1, wlh[1], accA, 0, 0, 0);
        accA = __builtin_amdgcn_mfma_f32_16x16x32_bf16(ah1, wll[1], accA, 0, 0, 0);
        accA = __builtin_amdgcn_mfma_f32_16x16x32_bf16(al1, wlh[1], accA, 0, 0, 0);
        accX = __builtin_amdgcn_mfma_f32_16x16x32_bf16(xh0, wrh[0], accX, 0, 0, 0);
        accX = __builtin_amdgcn_mfma_f32_16x16x32_bf16(xh0, wrl[0], accX, 0, 0, 0);
        accX = __builtin_amdgcn_mfma_f32_16x16x32_bf16(xl0, wrh[0], accX, 0, 0, 0);
        accX = __builtin_amdgcn_mfma_f32_16x16x32_bf16(xh1, wrh[1], accX, 0, 0, 0);
        accX = __builtin_amdgcn_mfma_f32_16x16x32_bf16(xh1, wrl[1], accX, 0, 0, 0);
        accX = __builtin_amdgcn_mfma_f32_16x16x32_bf16(xl1, wrh[1], accX, 0, 0, 0);

        int nb = (tile << 4) + (g << 2);
        if (AFF){
            int4 r4 = *(const int4*)(rs + nb);
            int  r5 = rs[nb + 4];
            int4 b4 = *(const int4*)(batch + nb);
            float hv;
            hv = accA[0] + accX[0] + bb + ((r4.y - r4.x) > 0 ? bd : 0.f);
            hv = leaky(hv); bs += hv; bq += hv*hv; POOL(b4.x, hv);
            hv = accA[1] + accX[1] + bb + ((r4.z - r4.y) > 0 ? bd : 0.f);
            hv = leaky(hv); bs += hv; bq += hv*hv; POOL(b4.y, hv);
            hv = accA[2] + accX[2] + bb + ((r4.w - r4.z) > 0 ? bd : 0.f);
            hv = leaky(hv); bs += hv; bq += hv*hv; POOL(b4.z, hv);
            hv = accA[3] + accX[3] + bb + ((r5 - r4.w) > 0 ? bd : 0.f);
            hv = leaky(hv); bs += hv; bq += hv*hv; POOL(b4.w, hv);
        } else {
            #pragma unroll
            for (int q = 0; q < 4; ++q){
                float hv = leaky(accA[q] + accX[q] + bb);
                hout[((size_t)(nb + q) << 6) + j] = hv;
                bs += hv; bq += hv*hv;
            }
        }
    };

    float4 A0[4], X0[4], A1[4], X1[4];
    bool act0 = (bt + 0) < NTILES, act1 = (bt + 1) < NTILES;
    bool act2 = (bt + 2) < NTILES, act3 = (bt + 3) < NTILES;
    if (act0) LOAD(bt + 0, A0, X0);
    if (act1) LOAD(bt + 1, A1, X1);
    if (act0) COMPUTE(bt + 0, A0, X0);
    if (act2) LOAD(bt + 2, A0, X0);
    if (act1) COMPUTE(bt + 1, A1, X1);
    if (act3) LOAD(bt + 3, A1, X1);
    if (act2) COMPUTE(bt + 2, A0, X0);
    if (act3) COMPUTE(bt + 3, A1, X1);

    bs += __shfl_xor(bs, 16, 64); bs += __shfl_xor(bs, 32, 64);
    bq += __shfl_xor(bq, 16, 64); bq += __shfl_xor(bq, 32, 64);
    if (lane < 16){
        atomicAdd(&bnsum[(jt << 4) + lane], bs);
        atomicAdd(&bnsq [(jt << 4) + lane], bq);
    }

    if (AFF){
        __syncthreads();
        int sp = min(span, 8);
        for (int i = t; i < (sp << 6); i += 256){
            float v = sS[i];
            if (v != 0.f) atomicAdd(&S[((gbase + (i >> 6)) << 6) + (i & 63)], v);
        }
    }
}

// ============ BN finalize ============
__global__ void k_bnfin(const float* __restrict__ sum, const float* __restrict__ sumsq,
                        const float* __restrict__ gamma, const float* __restrict__ beta,
                        float* __restrict__ scale, float* __restrict__ shift){
    int j = threadIdx.x;
    if (j < FDIM){
        float mu  = sum[j]   * (1.0f/N_NODES);
        float var = sumsq[j] * (1.0f/N_NODES) - mu*mu;
        float sc  = gamma[j] * rsqrtf(var + EPSV);
        scale[j] = sc;
        shift[j] = beta[j] - mu*sc;
    }
}

// ============ final MLP (pool finalize fused): one block per graph ============
__global__ __launch_bounds__(256) void k_mlp(
    const float* __restrict__ S, const int* __restrict__ batch,
    const float* __restrict__ scale, const float* __restrict__ shift,
    const float* __restrict__ gf,
    const float* __restrict__ Wm0, const float* __restrict__ bm0,
    const float* __restrict__ Wm1, const float* __restrict__ bm1,
    const float* __restrict__ Wm2, const float* __restrict__ bm2,
    float* __restrict__ out)
{
    __shared__ int seg[2];
    __shared__ float z[128];
    __shared__ float h1[256];
    __shared__ float h2[128];
    int g = blockIdx.x, t = threadIdx.x;
    if (t < 2){
        int target = g + t;
        int lo = 0, hi = N_NODES;
        while (lo < hi){ int mid = (lo+hi)>>1; if (batch[mid] < target) lo = mid+1; else hi = mid; }
        seg[t] = lo;
    }
    __syncthreads();
    float cnt = (float)(seg[1] - seg[0]);
    if (t < 64)
        z[t] = (scale[t]*S[(g<<6)+t] + cnt*shift[t]) / fmaxf(cnt, 1.f);
    else if (t < 128)
        z[t] = gf[g*64 + (t-64)];
    __syncthreads();
    float acc = bm0[t];
    #pragma unroll 8
    for (int k = 0; k < 128; ++k) acc += z[k]*Wm0[k*256 + t];
    h1[t] = leaky(acc);
    __syncthreads();
    if (t < 128){
        float a = bm1[t];
        #pragma unroll 8
        for (int k = 0; k < 256; ++k) a += h1[k]*Wm1[k*128 + t];
        h2[t] = leaky(a);
    }
    __syncthreads();
    if (t < 2){
        float a = bm2[t];
        for (int k = 0; k < 128; ++k) a += h2[k]*Wm2[k*2 + t];
        out[g*2 + t] = a;
    }
}

extern "C" void kernel_launch(void* const* d_in, const int* in_sizes, int n_in,
                              void* d_out, int out_size, void* d_ws, size_t ws_size,
                              hipStream_t stream) {
    const float* x     = (const float*)d_in[0];
    const int*   ei    = (const int*)d_in[1];
    const float* gf    = (const float*)d_in[2];
    const int*   batch = (const int*)d_in[3];
    const float* Wl0 = (const float*)d_in[4];
    const float* bl0 = (const float*)d_in[5];
    const float* Wr0 = (const float*)d_in[6];
    const float* g0  = (const float*)d_in[7];
    const float* b0  = (const float*)d_in[8];
    const float* Wl1 = (const float*)d_in[9];
    const float* bl1 = (const float*)d_in[10];
    const float* Wr1 = (const float*)d_in[11];
    const float* g1  = (const float*)d_in[12];
    const float* b1  = (const float*)d_in[13];
    const float* Wm0 = (const float*)d_in[14];
    const float* bm0 = (const float*)d_in[15];
    const float* Wm1 = (const float*)d_in[16];
    const float* bm1 = (const float*)d_in[17];
    const float* Wm2 = (const float*)d_in[18];
    const float* bm2 = (const float*)d_in[19];

    // ---- workspace ----
    int*   bhist  = (int*)d_ws;                      // [NB]
    int*   boff   = bhist + NB;                      // [NB+1]
    int*   cur    = boff + NB + 1;                   // [NB]
    int*   packed = (int*)d_ws + 2348;               // [E]
    int*   rs     = packed + N_EDGES;                // [N+1] (pad 100004)
    int*   col    = rs + 100004;                     // [E]
    float* bufA   = (float*)(col + N_EDGES);         // [N,64] agg1, then agg2
    float* bufB   = bufA + (size_t)N_NODES*FDIM;     // [N,64] h1
    float* bnsum  = bufB + (size_t)N_NODES*FDIM;     // [64]
    float* bnsq   = bnsum + 64;                      // [64]
    float* S      = bnsum + 128;                     // [128*64]
    float* scale0 = S + N_GRAPHS*FDIM;
    float* shift0 = scale0 + 64;
    float* scale1 = scale0 + 128;
    float* shift1 = scale0 + 192;

    const int* srcp = ei;
    const int* dstp = ei + N_EDGES;

    // ---- bucketed CSR build ----
    hipMemsetAsync(bhist, 0, NB*sizeof(int), stream);
    k_bh<<<PART_BLOCKS, 256, 0, stream>>>(dstp, bhist);
    k_bscan<<<1, 256, 0, stream>>>(bhist, boff, cur);
    k_part<<<PART_BLOCKS, 256, 0, stream>>>(srcp, dstp, cur, packed);
    k_sort<<<NB, 256, 0, stream>>>(packed, boff, rs, col);

    // ---- layer 1 ----
    hipMemsetAsync(bnsum, 0, 128*sizeof(float), stream);
    k_agg<<<2048, 256, 0, stream>>>(x, rs, col, bufA);
    k_gemm<false><<<GEMM_BLOCKS, 256, 0, stream>>>(bufA, x, bufB, rs, batch,
                                                   Wl0, bl0, Wr0, nullptr, nullptr,
                                                   bnsum, bnsq, nullptr);
    k_bnfin<<<1, 64, 0, stream>>>(bnsum, bnsq, g0, b0, scale0, shift0);

    // ---- layer 2 (h2 never materialized; pooling fused) ----
    hipMemsetAsync(bnsum, 0, (128 + N_GRAPHS*FDIM)*sizeof(float), stream);
    k_agg<<<2048, 256, 0, stream>>>(bufB, rs, col, bufA);
    k_gemm<true><<<GEMM_BLOCKS, 256, 0, stream>>>(bufA, bufB, nullptr, rs, batch,
                                                  Wl1, bl1, Wr1, scale0, shift0,
                                                  bnsum, bnsq, S);
    k_bnfin<<<1, 64, 0, stream>>>(bnsum, bnsq, g1, b1, scale1, shift1);

    // ---- pooling finalize + MLP ----
    k_mlp<<<N_GRAPHS, 256, 0, stream>>>(S, batch, scale1, shift1, gf,
                                        Wm0, bm0, Wm1, bm1, Wm2, bm2, (float*)d_out);
}

// Round 9
// 331.496 us; speedup vs baseline: 1.3464x; 1.0566x over previous
//
#include <hip/hip_runtime.h>

#define N_NODES 100000
#define N_EDGES 1600000
#define N_GRAPHS 128
#define FDIM 64
#define EPSV 1e-5f
#define NEG 0.01f

#define NB 782              // ceil(N_NODES/128) dst-range buckets
#define PART_BLOCKS 391     // ceil(N_EDGES/4096)
#define NTILES 6250         // N_NODES/16 (exact)
#define GEMM_BLOCKS 1563    // ceil(NTILES/4)

typedef short bf16x8 __attribute__((ext_vector_type(8)));
typedef float f32x4  __attribute__((ext_vector_type(4)));

__device__ __forceinline__ float leaky(float x){ return x >= 0.f ? x : NEG*x; }

__device__ __forceinline__ unsigned short f2bf(float x){          // RN-even
    unsigned u = __float_as_uint(x);
    return (unsigned short)((u + 0x7fffu + ((u >> 16) & 1u)) >> 16);
}
__device__ __forceinline__ float bf2f(unsigned short b){
    return __uint_as_float(((unsigned)b) << 16);
}

// truncation hi/lo split for fp32 GEMM inputs
__device__ __forceinline__ void split8(const float4& v0, const float4& v1,
                                       bf16x8& hi, bf16x8& lo){
    float f[8] = {v0.x, v0.y, v0.z, v0.w, v1.x, v1.y, v1.z, v1.w};
    #pragma unroll
    for (int i = 0; i < 8; ++i){
        unsigned u = __float_as_uint(f[i]);
        hi[i] = (short)(u >> 16);
        float lf = f[i] - __uint_as_float(u & 0xffff0000u);   // exact
        lo[i] = (short)(__float_as_uint(lf) >> 16);
    }
}

// ================= fp32 -> bf16 conversion (x) =================
__global__ __launch_bounds__(256) void k_cvt(const float* __restrict__ x,
                                             unsigned short* __restrict__ o){
    int i = blockIdx.x*256 + threadIdx.x;        // 1.6M threads, 4 elems each
    if (i < (N_NODES*FDIM)/4){
        float4 v = ((const float4*)x)[i];
        ushort4 r;
        r.x = f2bf(v.x); r.y = f2bf(v.y); r.z = f2bf(v.z); r.w = f2bf(v.w);
        ((ushort4*)o)[i] = r;
    }
}

// ================= bucket histogram (782 bins, LDS-reduced) =================
__global__ __launch_bounds__(256) void k_bh(const int* __restrict__ dst, int* __restrict__ bhist){
    __shared__ int lh[NB];
    int t = threadIdx.x;
    for (int i = t; i < NB; i += 256) lh[i] = 0;
    __syncthreads();
    int base = blockIdx.x * 4096;
    #pragma unroll
    for (int k = 0; k < 16; ++k){
        int e = base + k*256 + t;
        if (e < N_EDGES) atomicAdd(&lh[dst[e] >> 7], 1);
    }
    __syncthreads();
    for (int i = t; i < NB; i += 256) if (lh[i]) atomicAdd(&bhist[i], lh[i]);
}

// ================= single-block exclusive scan of NB bucket sizes =================
__global__ __launch_bounds__(256) void k_bscan(const int* __restrict__ bhist,
                                               int* __restrict__ boff, int* __restrict__ cur){
    __shared__ int lds[256];
    int t = threadIdx.x;
    int base = t*4;
    int v0 = (base+0 < NB) ? bhist[base+0] : 0;
    int v1 = (base+1 < NB) ? bhist[base+1] : 0;
    int v2 = (base+2 < NB) ? bhist[base+2] : 0;
    int v3 = (base+3 < NB) ? bhist[base+3] : 0;
    lds[t] = v0+v1+v2+v3; __syncthreads();
    for (int off = 1; off < 256; off <<= 1){
        int add = (t >= off) ? lds[t-off] : 0; __syncthreads();
        lds[t] += add; __syncthreads();
    }
    int excl = (t > 0) ? lds[t-1] : 0;
    int p0 = excl, p1 = excl+v0, p2 = excl+v0+v1, p3 = excl+v0+v1+v2;
    if (base+0 < NB){ boff[base+0] = p0; cur[base+0] = p0; }
    if (base+1 < NB){ boff[base+1] = p1; cur[base+1] = p1; }
    if (base+2 < NB){ boff[base+2] = p2; cur[base+2] = p2; }
    if (base+3 < NB){ boff[base+3] = p3; cur[base+3] = p3; }
    if (t == 0) boff[NB] = N_EDGES;
}

// ================= partition edges into dst buckets, packed (src<<7)|dst_local =================
__global__ __launch_bounds__(256) void k_part(const int* __restrict__ src, const int* __restrict__ dst,
                                              int* __restrict__ cur, int* __restrict__ packed){
    __shared__ int lh[NB];
    __shared__ int lc[NB];
    int t = threadIdx.x;
    for (int i = t; i < NB; i += 256) lh[i] = 0;
    __syncthreads();
    int base = blockIdx.x * 4096;
    int d[16];
    #pragma unroll
    for (int k = 0; k < 16; ++k){
        int e = base + k*256 + t;
        d[k] = (e < N_EDGES) ? dst[e] : -1;
        if (d[k] >= 0) atomicAdd(&lh[d[k] >> 7], 1);
    }
    __syncthreads();
    for (int i = t; i < NB; i += 256) lc[i] = atomicAdd(&cur[i], lh[i]);
    __syncthreads();
    #pragma unroll
    for (int k = 0; k < 16; ++k){
        int e = base + k*256 + t;
        if (e < N_EDGES){
            int b = d[k] >> 7;
            int p = atomicAdd(&lc[b], 1);
            packed[p] = (src[e] << 7) | (d[k] & 127);
        }
    }
}

// ======== per-bucket counting sort: packed bucket -> CSR (rs + col) ========
__global__ __launch_bounds__(256) void k_sort(const int* __restrict__ packed,
                                              const int* __restrict__ boff,
                                              int* __restrict__ rs, int* __restrict__ col){
    __shared__ int hist[128];
    __shared__ int curs[128];
    int b = blockIdx.x, t = threadIdx.x;
    int e0 = boff[b], e1 = boff[b+1];
    if (t < 128) hist[t] = 0;
    __syncthreads();
    for (int e = e0 + t; e < e1; e += 256)
        atomicAdd(&hist[packed[e] & 127], 1);
    __syncthreads();
    int cnt = (t < 128) ? hist[t] : 0;
    __syncthreads();
    for (int off = 1; off < 128; off <<= 1){
        int add = (t < 128 && t >= off) ? hist[t-off] : 0;
        __syncthreads();
        if (t < 128) hist[t] += add;
        __syncthreads();
    }
    int nbase = b << 7;
    int nloc = min(128, N_NODES - nbase);
    if (t < nloc){
        int excl = hist[t] - cnt;
        rs[nbase + t] = e0 + excl;
        curs[t] = excl;
    }
    __syncthreads();
    for (int e = e0 + t; e < e1; e += 256){
        int v = packed[e];
        int p = atomicAdd(&curs[v & 127], 1);
        col[e0 + p] = ((unsigned)v) >> 7;
    }
    if (b == 0 && t == 0) rs[N_NODES] = N_EDGES;
}

// ============ bf16 gather-mean: wave per node, 16 lanes x ushort4 (8B), fp32 accum ============
__global__ __launch_bounds__(256) void k_agg(
    const unsigned short* __restrict__ xin, const int* __restrict__ rs,
    const int* __restrict__ col, float* __restrict__ agg)
{
    int t = threadIdx.x;
    int lane = t & 63;
    int sub = lane >> 4;          // edge slot 0..3
    int q   = lane & 15;          // feature quad
    int wid = (blockIdx.x << 2) + (t >> 6);
    const int nw = gridDim.x << 2;
    for (int n = wid; n < N_NODES; n += nw){
        int e0 = __builtin_amdgcn_readfirstlane(rs[n]);
        int e1 = __builtin_amdgcn_readfirstlane(rs[n+1]);
        float ax=0.f, ay=0.f, az=0.f, aw=0.f;
        for (int e = e0; e < e1; e += 16){
            int i0 = e + sub, i1 = e + 4 + sub, i2 = e + 8 + sub, i3 = e + 12 + sub;
            if (i0 < e1){
                uint2 u = ((const uint2*)(xin + ((size_t)col[i0] << 6)))[q];
                ax += __uint_as_float(u.x << 16); ay += __uint_as_float(u.x & 0xffff0000u);
                az += __uint_as_float(u.y << 16); aw += __uint_as_float(u.y & 0xffff0000u);
            }
            if (i1 < e1){
                uint2 u = ((const uint2*)(xin + ((size_t)col[i1] << 6)))[q];
                ax += __uint_as_float(u.x << 16); ay += __uint_as_float(u.x & 0xffff0000u);
                az += __uint_as_float(u.y << 16); aw += __uint_as_float(u.y & 0xffff0000u);
            }
            if (i2 < e1){
                uint2 u = ((const uint2*)(xin + ((size_t)col[i2] << 6)))[q];
                ax += __uint_as_float(u.x << 16); ay += __uint_as_float(u.x & 0xffff0000u);
                az += __uint_as_float(u.y << 16); aw += __uint_as_float(u.y & 0xffff0000u);
            }
            if (i3 < e1){
                uint2 u = ((const uint2*)(xin + ((size_t)col[i3] << 6)))[q];
                ax += __uint_as_float(u.x << 16); ay += __uint_as_float(u.x & 0xffff0000u);
                az += __uint_as_float(u.y << 16); aw += __uint_as_float(u.y & 0xffff0000u);
            }
        }
        ax += __shfl_xor(ax, 16, 64); ay += __shfl_xor(ay, 16, 64);
        az += __shfl_xor(az, 16, 64); aw += __shfl_xor(aw, 16, 64);
        ax += __shfl_xor(ax, 32, 64); ay += __shfl_xor(ay, 32, 64);
        az += __shfl_xor(az, 32, 64); aw += __shfl_xor(aw, 32, 64);
        if (sub == 0){
            float rd = 1.f / fmaxf((float)(e1 - e0), 1.f);
            // lane q covers features q*4..q*4+3
            float4 o = make_float4(ax*rd, ay*rd, az*rd, aw*rd);
            ((float4*)(agg + ((size_t)n << 6)))[q] = o;
        }
    }
}

// ============ MFMA dual-GEMM, barrier-free, double-buffered tile pipeline ============
// XBF: X-branch input is bf16 (h1) -> direct fragment load, 2-term product.
// !AFF: h output stored as bf16 only.
template<bool AFF, bool XBF>
__global__ __launch_bounds__(256) void k_gemm(
    const float* __restrict__ agg,
    const float* __restrict__ xf, const unsigned short* __restrict__ xbf,
    unsigned short* __restrict__ hout,
    const int* __restrict__ rs, const int* __restrict__ batch,
    const float* __restrict__ Wl, const float* __restrict__ bl,
    const float* __restrict__ Wr,
    const float* __restrict__ scale, const float* __restrict__ shift,
    float* __restrict__ bnsum, float* __restrict__ bnsq,
    float* __restrict__ S)
{
    __shared__ float sS[8*64];     // per-block graph-pool bins (AFF only)
    int t = threadIdx.x;
    int lane = t & 63;
    int jt = t >> 6;
    int g = lane >> 4, r = lane & 15;
    int j = (jt << 4) + r;

    bf16x8 wlh[2], wll[2], wrh[2], wrl[2];
    #pragma unroll
    for (int ks = 0; ks < 2; ++ks){
        #pragma unroll
        for (int i = 0; i < 8; ++i){
            int k = (ks << 5) + (g << 3) + i;
            float s = AFF ? scale[k] : 1.f;
            float wv = Wl[(k << 6) + j] * s;
            unsigned u = __float_as_uint(wv);
            wlh[ks][i] = (short)(u >> 16);
            float lf = wv - __uint_as_float(u & 0xffff0000u);
            wll[ks][i] = (short)(__float_as_uint(lf) >> 16);
            wv = Wr[(k << 6) + j] * s;
            u = __float_as_uint(wv);
            wrh[ks][i] = (short)(u >> 16);
            lf = wv - __uint_as_float(u & 0xffff0000u);
            wrl[ks][i] = (short)(__float_as_uint(lf) >> 16);
        }
    }

    float bb = bl[j], bd = 0.f;
    if (AFF){
        #pragma unroll 8
        for (int k = 0; k < 64; ++k){
            float sh = shift[k];
            bb += sh * Wr[(k << 6) + j];
            bd += sh * Wl[(k << 6) + j];
        }
    }

    int gbase = 0, span = 0;
    if (AFF){
        for (int i = t; i < 512; i += 256) sS[i] = 0.f;
        int nfirst = blockIdx.x << 6;
        int nlast  = min(nfirst + 63, N_NODES - 1);
        gbase = batch[nfirst];
        span  = batch[nlast] - gbase + 1;
        __syncthreads();
    }

    float bs = 0.f, bq = 0.f;
    int bt = blockIdx.x << 2;

    auto LOADA = [&](int tile, float4* A){
        size_t rowoff = (((size_t)((tile << 4) + r)) << 6) + (g << 3);
        const float4* pa = (const float4*)(agg + rowoff);
        A[0] = pa[0]; A[1] = pa[1]; A[2] = pa[8]; A[3] = pa[9];
    };
    auto LOADXF = [&](int tile, float4* X){
        size_t rowoff = (((size_t)((tile << 4) + r)) << 6) + (g << 3);
        const float4* px = (const float4*)(xf + rowoff);
        X[0] = px[0]; X[1] = px[1]; X[2] = px[8]; X[3] = px[9];
    };
    auto LOADXB = [&](int tile, bf16x8* XH){
        size_t rowoff = (((size_t)((tile << 4) + r)) << 6) + (g << 3);
        const bf16x8* px = (const bf16x8*)(xbf + rowoff);
        XH[0] = px[0];      // k 0..7 of ks=0 slice
        XH[1] = px[4];      // +32 ushorts -> ks=1 slice
    };

    auto POOL = [&](int gr, float hv){
        int lg = gr - gbase;
        if (lg < 8) atomicAdd(&sS[(lg << 6) + j], hv);
        else        atomicAdd(&S[(gr << 6) + j], hv);
    };

    auto COMPUTE = [&](int tile, const float4* A, const float4* X, const bf16x8* XH){
        bf16x8 ah0, al0, ah1, al1;
        split8(A[0], A[1], ah0, al0);
        split8(A[2], A[3], ah1, al1);
        f32x4 accA = {0.f, 0.f, 0.f, 0.f};
        f32x4 accX = {0.f, 0.f, 0.f, 0.f};
        accA = __builtin_amdgcn_mfma_f32_16x16x32_bf16(ah0, wlh[0], accA, 0, 0, 0);
        accA = __builtin_amdgcn_mfma_f32_16x16x32_bf16(ah0, wll[0], accA, 0, 0, 0);
        accA = __builtin_amdgcn_mfma_f32_16x16x32_bf16(al0, wlh[0], accA, 0, 0, 0);
        accA = __builtin_amdgcn_mfma_f32_16x16x32_bf16(ah1, wlh[1], accA, 0, 0, 0);
        accA = __builtin_amdgcn_mfma_f32_16x16x32_bf16(ah1, wll[1], accA, 0, 0, 0);
        accA = __builtin_amdgcn_mfma_f32_16x16x32_bf16(al1, wlh[1], accA, 0, 0, 0);
        if constexpr (XBF){
            accX = __builtin_amdgcn_mfma_f32_16x16x32_bf16(XH[0], wrh[0], accX, 0, 0, 0);
            accX = __builtin_amdgcn_mfma_f32_16x16x32_bf16(XH[0], wrl[0], accX, 0, 0, 0);
            accX = __builtin_amdgcn_mfma_f32_16x16x32_bf16(XH[1], wrh[1], accX, 0, 0, 0);
            accX = __builtin_amdgcn_mfma_f32_16x16x32_bf16(XH[1], wrl[1], accX, 0, 0, 0);
        } else {
            bf16x8 xh0, xl0, xh1, xl1;
            split8(X[0], X[1], xh0, xl0);
            split8(X[2], X[3], xh1, xl1);
            accX = __builtin_amdgcn_mfma_f32_16x16x32_bf16(xh0, wrh[0], accX, 0, 0, 0);
            accX = __builtin_amdgcn_mfma_f32_16x16x32_bf16(xh0, wrl[0], accX, 0, 0, 0);
            accX = __builtin_amdgcn_mfma_f32_16x16x32_bf16(xl0, wrh[0], accX, 0, 0, 0);
            accX = __builtin_amdgcn_mfma_f32_16x16x32_bf16(xh1, wrh[1], accX, 0, 0, 0);
            accX = __builtin_amdgcn_mfma_f32_16x16x32_bf16(xh1, wrl[1], accX, 0, 0, 0);
            accX = __builtin_amdgcn_mfma_f32_16x16x32_bf16(xl1, wrh[1], accX, 0, 0, 0);
        }

        int nb = (tile << 4) + (g << 2);
        if (AFF){
            int4 r4 = *(const int4*)(rs + nb);
            int  r5 = rs[nb + 4];
            int4 b4 = *(const int4*)(batch + nb);
            float hv;
            hv = accA[0] + accX[0] + bb + ((r4.y - r4.x) > 0 ? bd : 0.f);
            hv = leaky(hv); bs += hv; bq += hv*hv; POOL(b4.x, hv);
            hv = accA[1] + accX[1] + bb + ((r4.z - r4.y) > 0 ? bd : 0.f);
            hv = leaky(hv); bs += hv; bq += hv*hv; POOL(b4.y, hv);
            hv = accA[2] + accX[2] + bb + ((r4.w - r4.z) > 0 ? bd : 0.f);
            hv = leaky(hv); bs += hv; bq += hv*hv; POOL(b4.z, hv);
            hv = accA[3] + accX[3] + bb + ((r5 - r4.w) > 0 ? bd : 0.f);
            hv = leaky(hv); bs += hv; bq += hv*hv; POOL(b4.w, hv);
        } else {
            #pragma unroll
            for (int q = 0; q < 4; ++q){
                float hv = leaky(accA[q] + accX[q] + bb);
                unsigned short h16 = f2bf(hv);
                float hr = bf2f(h16);
                hout[((size_t)(nb + q) << 6) + j] = h16;
                bs += hr; bq += hr*hr;
            }
        }
    };

    float4 A0[4], X0[4], A1[4], X1[4];
    bf16x8 XH0[2], XH1[2];
    bool act0 = (bt + 0) < NTILES, act1 = (bt + 1) < NTILES;
    bool act2 = (bt + 2) < NTILES, act3 = (bt + 3) < NTILES;
    if (act0){ LOADA(bt+0, A0); if constexpr (XBF) LOADXB(bt+0, XH0); else LOADXF(bt+0, X0); }
    if (act1){ LOADA(bt+1, A1); if constexpr (XBF) LOADXB(bt+1, XH1); else LOADXF(bt+1, X1); }
    if (act0) COMPUTE(bt+0, A0, X0, XH0);
    if (act2){ LOADA(bt+2, A0); if constexpr (XBF) LOADXB(bt+2, XH0); else LOADXF(bt+2, X0); }
    if (act1) COMPUTE(bt+1, A1, X1, XH1);
    if (act3){ LOADA(bt+3, A1); if constexpr (XBF) LOADXB(bt+3, XH1); else LOADXF(bt+3, X1); }
    if (act2) COMPUTE(bt+2, A0, X0, XH0);
    if (act3) COMPUTE(bt+3, A1, X1, XH1);

    bs += __shfl_xor(bs, 16, 64); bs += __shfl_xor(bs, 32, 64);
    bq += __shfl_xor(bq, 16, 64); bq += __shfl_xor(bq, 32, 64);
    if (lane < 16){
        atomicAdd(&bnsum[(jt << 4) + lane], bs);
        atomicAdd(&bnsq [(jt << 4) + lane], bq);
    }

    if (AFF){
        __syncthreads();
        int sp = min(span, 8);
        for (int i = t; i < (sp << 6); i += 256){
            float v = sS[i];
            if (v != 0.f) atomicAdd(&S[((gbase + (i >> 6)) << 6) + (i & 63)], v);
        }
    }
}

// ============ BN finalize ============
__global__ void k_bnfin(const float* __restrict__ sum, const float* __restrict__ sumsq,
                        const float* __restrict__ gamma, const float* __restrict__ beta,
                        float* __restrict__ scale, float* __restrict__ shift){
    int j = threadIdx.x;
    if (j < FDIM){
        float mu  = sum[j]   * (1.0f/N_NODES);
        float var = sumsq[j] * (1.0f/N_NODES) - mu*mu;
        float sc  = gamma[j] * rsqrtf(var + EPSV);
        scale[j] = sc;
        shift[j] = beta[j] - mu*sc;
    }
}

// ============ final MLP (pool finalize fused): one block per graph ============
__global__ __launch_bounds__(256) void k_mlp(
    const float* __restrict__ S, const int* __restrict__ batch,
    const float* __restrict__ scale, const float* __restrict__ shift,
    const float* __restrict__ gf,
    const float* __restrict__ Wm0, const float* __restrict__ bm0,
    const float* __restrict__ Wm1, const float* __restrict__ bm1,
    const float* __restrict__ Wm2, const float* __restrict__ bm2,
    float* __restrict__ out)
{
    __shared__ int seg[2];
    __shared__ float z[128];
    __shared__ float h1[256];
    __shared__ float h2[128];
    int g = blockIdx.x, t = threadIdx.x;
    if (t < 2){
        int target = g + t;
        int lo = 0, hi = N_NODES;
        while (lo < hi){ int mid = (lo+hi)>>1; if (batch[mid] < target) lo = mid+1; else hi = mid; }
        seg[t] = lo;
    }
    __syncthreads();
    float cnt = (float)(seg[1] - seg[0]);
    if (t < 64)
        z[t] = (scale[t]*S[(g<<6)+t] + cnt*shift[t]) / fmaxf(cnt, 1.f);
    else if (t < 128)
        z[t] = gf[g*64 + (t-64)];
    __syncthreads();
    float acc = bm0[t];
    #pragma unroll 8
    for (int k = 0; k < 128; ++k) acc += z[k]*Wm0[k*256 + t];
    h1[t] = leaky(acc);
    __syncthreads();
    if (t < 128){
        float a = bm1[t];
        #pragma unroll 8
        for (int k = 0; k < 256; ++k) a += h1[k]*Wm1[k*128 + t];
        h2[t] = leaky(a);
    }
    __syncthreads();
    if (t < 2){
        float a = bm2[t];
        for (int k = 0; k < 128; ++k) a += h2[k]*Wm2[k*2 + t];
        out[g*2 + t] = a;
    }
}

extern "C" void kernel_launch(void* const* d_in, const int* in_sizes, int n_in,
                              void* d_out, int out_size, void* d_ws, size_t ws_size,
                              hipStream_t stream) {
    const float* x     = (const float*)d_in[0];
    const int*   ei    = (const int*)d_in[1];
    const float* gf    = (const float*)d_in[2];
    const int*   batch = (const int*)d_in[3];
    const float* Wl0 = (const float*)d_in[4];
    const float* bl0 = (const float*)d_in[5];
    const float* Wr0 = (const float*)d_in[6];
    const float* g0  = (const float*)d_in[7];
    const float* b0  = (const float*)d_in[8];
    const float* Wl1 = (const float*)d_in[9];
    const float* bl1 = (const float*)d_in[10];
    const float* Wr1 = (const float*)d_in[11];
    const float* g1  = (const float*)d_in[12];
    const float* b1  = (const float*)d_in[13];
    const float* Wm0 = (const float*)d_in[14];
    const float* bm0 = (const float*)d_in[15];
    const float* Wm1 = (const float*)d_in[16];
    const float* bm1 = (const float*)d_in[17];
    const float* Wm2 = (const float*)d_in[18];
    const float* bm2 = (const float*)d_in[19];

    // ---- workspace ----
    int*   bhist  = (int*)d_ws;                      // [NB]
    int*   boff   = bhist + NB;                      // [NB+1]
    int*   cur    = boff + NB + 1;                   // [NB]
    int*   packed = (int*)d_ws + 2348;               // [E]
    int*   rs     = packed + N_EDGES;                // [N+1] (pad 100004)
    int*   col    = rs + 100004;                     // [E]
    unsigned short* xbf  = (unsigned short*)(col + N_EDGES);  // [N*64] bf16 x
    unsigned short* h1bf = xbf + (size_t)N_NODES*FDIM;        // [N*64] bf16 h1
    float* bufA   = (float*)(h1bf + (size_t)N_NODES*FDIM);    // [N,64] fp32 agg (both layers)
    float* bnsum  = bufA + (size_t)N_NODES*FDIM;     // [64]
    float* bnsq   = bnsum + 64;                      // [64]
    float* S      = bnsum + 128;                     // [128*64]
    float* scale0 = S + N_GRAPHS*FDIM;
    float* shift0 = scale0 + 64;
    float* scale1 = scale0 + 128;
    float* shift1 = scale0 + 192;

    const int* srcp = ei;
    const int* dstp = ei + N_EDGES;

    // ---- bucketed CSR build + x conversion ----
    hipMemsetAsync(bhist, 0, NB*sizeof(int), stream);
    k_cvt<<<(N_NODES*FDIM/4 + 255)/256, 256, 0, stream>>>(x, xbf);
    k_bh<<<PART_BLOCKS, 256, 0, stream>>>(dstp, bhist);
    k_bscan<<<1, 256, 0, stream>>>(bhist, boff, cur);
    k_part<<<PART_BLOCKS, 256, 0, stream>>>(srcp, dstp, cur, packed);
    k_sort<<<NB, 256, 0, stream>>>(packed, boff, rs, col);

    // ---- layer 1 ----
    hipMemsetAsync(bnsum, 0, 128*sizeof(float), stream);
    k_agg<<<2048, 256, 0, stream>>>(xbf, rs, col, bufA);
    k_gemm<false, false><<<GEMM_BLOCKS, 256, 0, stream>>>(
        bufA, x, nullptr, h1bf, rs, batch,
        Wl0, bl0, Wr0, nullptr, nullptr, bnsum, bnsq, nullptr);
    k_bnfin<<<1, 64, 0, stream>>>(bnsum, bnsq, g0, b0, scale0, shift0);

    // ---- layer 2 (h2 never materialized; pooling fused) ----
    hipMemsetAsync(bnsum, 0, (128 + N_GRAPHS*FDIM)*sizeof(float), stream);
    k_agg<<<2048, 256, 0, stream>>>(h1bf, rs, col, bufA);
    k_gemm<true, true><<<GEMM_BLOCKS, 256, 0, stream>>>(
        bufA, nullptr, h1bf, nullptr, rs, batch,
        Wl1, bl1, Wr1, scale0, shift0, bnsum, bnsq, S);
    k_bnfin<<<1, 64, 0, stream>>>(bnsum, bnsq, g1, b1, scale1, shift1);

    // ---- pooling finalize + MLP ----
    k_mlp<<<N_GRAPHS, 256, 0, stream>>>(S, batch, scale1, shift1, gf,
                                        Wm0, bm0, Wm1, bm1, Wm2, bm2, (float*)d_out);
}

// Round 10
// 300.769 us; speedup vs baseline: 1.4840x; 1.1022x over previous
//
#include <hip/hip_runtime.h>

#define N_NODES 100000
#define N_EDGES 1600000
#define N_GRAPHS 128
#define FDIM 64
#define EPSV 1e-5f
#define NEG 0.01f

#define NB 782              // ceil(N_NODES/128) dst-range buckets
#define PART_BLOCKS 391     // ceil(N_EDGES/4096)
#define NTILES 6250         // N_NODES/16 (exact)
#define TPB 8               // tiles per gemm block
#define GEMM_BLOCKS 782     // ceil(NTILES/TPB)

typedef short bf16x8 __attribute__((ext_vector_type(8)));
typedef float f32x4  __attribute__((ext_vector_type(4)));

__device__ __forceinline__ float leaky(float x){ return x >= 0.f ? x : NEG*x; }

__device__ __forceinline__ unsigned short f2bf(float x){          // RN-even
    unsigned u = __float_as_uint(x);
    return (unsigned short)((u + 0x7fffu + ((u >> 16) & 1u)) >> 16);
}
__device__ __forceinline__ float bf2f(unsigned short b){
    return __uint_as_float(((unsigned)b) << 16);
}

// truncation hi/lo split for fp32 GEMM inputs
__device__ __forceinline__ void split8(const float4& v0, const float4& v1,
                                       bf16x8& hi, bf16x8& lo){
    float f[8] = {v0.x, v0.y, v0.z, v0.w, v1.x, v1.y, v1.z, v1.w};
    #pragma unroll
    for (int i = 0; i < 8; ++i){
        unsigned u = __float_as_uint(f[i]);
        hi[i] = (short)(u >> 16);
        float lf = f[i] - __uint_as_float(u & 0xffff0000u);   // exact
        lo[i] = (short)(__float_as_uint(lf) >> 16);
    }
}

// ================= fp32 -> bf16 conversion (x) =================
__global__ __launch_bounds__(256) void k_cvt(const float* __restrict__ x,
                                             unsigned short* __restrict__ o){
    int i = blockIdx.x*256 + threadIdx.x;
    if (i < (N_NODES*FDIM)/4){
        float4 v = ((const float4*)x)[i];
        ushort4 r;
        r.x = f2bf(v.x); r.y = f2bf(v.y); r.z = f2bf(v.z); r.w = f2bf(v.w);
        ((ushort4*)o)[i] = r;
    }
}

// ================= bucket histogram (782 bins, LDS-reduced) =================
__global__ __launch_bounds__(256) void k_bh(const int* __restrict__ dst, int* __restrict__ bhist){
    __shared__ int lh[NB];
    int t = threadIdx.x;
    for (int i = t; i < NB; i += 256) lh[i] = 0;
    __syncthreads();
    int base = blockIdx.x * 4096;
    #pragma unroll
    for (int k = 0; k < 16; ++k){
        int e = base + k*256 + t;
        if (e < N_EDGES) atomicAdd(&lh[dst[e] >> 7], 1);
    }
    __syncthreads();
    for (int i = t; i < NB; i += 256) if (lh[i]) atomicAdd(&bhist[i], lh[i]);
}

// ================= single-block exclusive scan of NB bucket sizes =================
__global__ __launch_bounds__(256) void k_bscan(const int* __restrict__ bhist,
                                               int* __restrict__ boff, int* __restrict__ cur){
    __shared__ int lds[256];
    int t = threadIdx.x;
    int base = t*4;
    int v0 = (base+0 < NB) ? bhist[base+0] : 0;
    int v1 = (base+1 < NB) ? bhist[base+1] : 0;
    int v2 = (base+2 < NB) ? bhist[base+2] : 0;
    int v3 = (base+3 < NB) ? bhist[base+3] : 0;
    lds[t] = v0+v1+v2+v3; __syncthreads();
    for (int off = 1; off < 256; off <<= 1){
        int add = (t >= off) ? lds[t-off] : 0; __syncthreads();
        lds[t] += add; __syncthreads();
    }
    int excl = (t > 0) ? lds[t-1] : 0;
    int p0 = excl, p1 = excl+v0, p2 = excl+v0+v1, p3 = excl+v0+v1+v2;
    if (base+0 < NB){ boff[base+0] = p0; cur[base+0] = p0; }
    if (base+1 < NB){ boff[base+1] = p1; cur[base+1] = p1; }
    if (base+2 < NB){ boff[base+2] = p2; cur[base+2] = p2; }
    if (base+3 < NB){ boff[base+3] = p3; cur[base+3] = p3; }
    if (t == 0) boff[NB] = N_EDGES;
}

// ================= partition edges into dst buckets, packed (src<<7)|dst_local =================
__global__ __launch_bounds__(256) void k_part(const int* __restrict__ src, const int* __restrict__ dst,
                                              int* __restrict__ cur, int* __restrict__ packed){
    __shared__ int lh[NB];
    __shared__ int lc[NB];
    int t = threadIdx.x;
    for (int i = t; i < NB; i += 256) lh[i] = 0;
    __syncthreads();
    int base = blockIdx.x * 4096;
    int d[16];
    #pragma unroll
    for (int k = 0; k < 16; ++k){
        int e = base + k*256 + t;
        d[k] = (e < N_EDGES) ? dst[e] : -1;
        if (d[k] >= 0) atomicAdd(&lh[d[k] >> 7], 1);
    }
    __syncthreads();
    for (int i = t; i < NB; i += 256) lc[i] = atomicAdd(&cur[i], lh[i]);
    __syncthreads();
    #pragma unroll
    for (int k = 0; k < 16; ++k){
        int e = base + k*256 + t;
        if (e < N_EDGES){
            int b = d[k] >> 7;
            int p = atomicAdd(&lc[b], 1);
            packed[p] = (src[e] << 7) | (d[k] & 127);
        }
    }
}

// ======== per-bucket counting sort: packed bucket -> CSR (rs + col) ========
__global__ __launch_bounds__(256) void k_sort(const int* __restrict__ packed,
                                              const int* __restrict__ boff,
                                              int* __restrict__ rs, int* __restrict__ col){
    __shared__ int hist[128];
    __shared__ int curs[128];
    int b = blockIdx.x, t = threadIdx.x;
    int e0 = boff[b], e1 = boff[b+1];
    if (t < 128) hist[t] = 0;
    __syncthreads();
    for (int e = e0 + t; e < e1; e += 256)
        atomicAdd(&hist[packed[e] & 127], 1);
    __syncthreads();
    int cnt = (t < 128) ? hist[t] : 0;
    __syncthreads();
    for (int off = 1; off < 128; off <<= 1){
        int add = (t < 128 && t >= off) ? hist[t-off] : 0;
        __syncthreads();
        if (t < 128) hist[t] += add;
        __syncthreads();
    }
    int nbase = b << 7;
    int nloc = min(128, N_NODES - nbase);
    if (t < nloc){
        int excl = hist[t] - cnt;
        rs[nbase + t] = e0 + excl;
        curs[t] = excl;
    }
    __syncthreads();
    for (int e = e0 + t; e < e1; e += 256){
        int v = packed[e];
        int p = atomicAdd(&curs[v & 127], 1);
        col[e0 + p] = ((unsigned)v) >> 7;
    }
    if (b == 0 && t == 0) rs[N_NODES] = N_EDGES;
}

// ============ bf16 gather-mean: wave per node, 16 lanes x 8B, fp32 accum ============
__global__ __launch_bounds__(256) void k_agg(
    const unsigned short* __restrict__ xin, const int* __restrict__ rs,
    const int* __restrict__ col, float* __restrict__ agg)
{
    int t = threadIdx.x;
    int lane = t & 63;
    int sub = lane >> 4;          // edge slot 0..3
    int q   = lane & 15;          // feature quad
    int wid = (blockIdx.x << 2) + (t >> 6);
    const int nw = gridDim.x << 2;
    for (int n = wid; n < N_NODES; n += nw){
        int e0 = __builtin_amdgcn_readfirstlane(rs[n]);
        int e1 = __builtin_amdgcn_readfirstlane(rs[n+1]);
        float ax=0.f, ay=0.f, az=0.f, aw=0.f;
        for (int e = e0; e < e1; e += 16){
            int i0 = e + sub, i1 = e + 4 + sub, i2 = e + 8 + sub, i3 = e + 12 + sub;
            if (i0 < e1){
                uint2 u = ((const uint2*)(xin + ((size_t)col[i0] << 6)))[q];
                ax += __uint_as_float(u.x << 16); ay += __uint_as_float(u.x & 0xffff0000u);
                az += __uint_as_float(u.y << 16); aw += __uint_as_float(u.y & 0xffff0000u);
            }
            if (i1 < e1){
                uint2 u = ((const uint2*)(xin + ((size_t)col[i1] << 6)))[q];
                ax += __uint_as_float(u.x << 16); ay += __uint_as_float(u.x & 0xffff0000u);
                az += __uint_as_float(u.y << 16); aw += __uint_as_float(u.y & 0xffff0000u);
            }
            if (i2 < e1){
                uint2 u = ((const uint2*)(xin + ((size_t)col[i2] << 6)))[q];
                ax += __uint_as_float(u.x << 16); ay += __uint_as_float(u.x & 0xffff0000u);
                az += __uint_as_float(u.y << 16); aw += __uint_as_float(u.y & 0xffff0000u);
            }
            if (i3 < e1){
                uint2 u = ((const uint2*)(xin + ((size_t)col[i3] << 6)))[q];
                ax += __uint_as_float(u.x << 16); ay += __uint_as_float(u.x & 0xffff0000u);
                az += __uint_as_float(u.y << 16); aw += __uint_as_float(u.y & 0xffff0000u);
            }
        }
        ax += __shfl_xor(ax, 16, 64); ay += __shfl_xor(ay, 16, 64);
        az += __shfl_xor(az, 16, 64); aw += __shfl_xor(aw, 16, 64);
        ax += __shfl_xor(ax, 32, 64); ay += __shfl_xor(ay, 32, 64);
        az += __shfl_xor(az, 32, 64); aw += __shfl_xor(aw, 32, 64);
        if (sub == 0){
            float rd = 1.f / fmaxf((float)(e1 - e0), 1.f);
            float4 o = make_float4(ax*rd, ay*rd, az*rd, aw*rd);
            ((float4*)(agg + ((size_t)n << 6)))[q] = o;
        }
    }
}

// ============ MFMA dual-GEMM, barrier-free, 8-tile pipelined, low-contention BN ============
template<bool AFF, bool XBF>
__global__ __launch_bounds__(256) void k_gemm(
    const float* __restrict__ agg,
    const float* __restrict__ xf, const unsigned short* __restrict__ xbf,
    unsigned short* __restrict__ hout,
    const int* __restrict__ rs, const int* __restrict__ batch,
    const float* __restrict__ Wl, const float* __restrict__ Wr,
    const float* __restrict__ scale,
    const float* __restrict__ bbias, const float* __restrict__ bdelta,
    float* __restrict__ bnpart, float* __restrict__ S)
{
    __shared__ float sS[8*64];     // per-block graph-pool bins (AFF only)
    int t = threadIdx.x;
    int lane = t & 63;
    int jt = t >> 6;
    int g = lane >> 4, r = lane & 15;
    int j = (jt << 4) + r;

    bf16x8 wlh[2], wll[2], wrh[2], wrl[2];
    #pragma unroll
    for (int ks = 0; ks < 2; ++ks){
        #pragma unroll
        for (int i = 0; i < 8; ++i){
            int k = (ks << 5) + (g << 3) + i;
            float s = AFF ? scale[k] : 1.f;
            float wv = Wl[(k << 6) + j] * s;
            unsigned u = __float_as_uint(wv);
            wlh[ks][i] = (short)(u >> 16);
            float lf = wv - __uint_as_float(u & 0xffff0000u);
            wll[ks][i] = (short)(__float_as_uint(lf) >> 16);
            wv = Wr[(k << 6) + j] * s;
            u = __float_as_uint(wv);
            wrh[ks][i] = (short)(u >> 16);
            lf = wv - __uint_as_float(u & 0xffff0000u);
            wrl[ks][i] = (short)(__float_as_uint(lf) >> 16);
        }
    }

    float bb = bbias[j];
    float bd = AFF ? bdelta[j] : 0.f;

    int gbase = 0, span = 0;
    if (AFF){
        for (int i = t; i < 512; i += 256) sS[i] = 0.f;
        int nfirst = blockIdx.x * (TPB*16);
        int nlast  = min(nfirst + TPB*16 - 1, N_NODES - 1);
        gbase = batch[nfirst];
        span  = batch[nlast] - gbase + 1;
        __syncthreads();
    }

    float bs = 0.f, bq = 0.f;
    int c0 = blockIdx.x * TPB;
    int cend = min(c0 + TPB, NTILES);

    auto LOADT = [&](int tile, float4* A, float4* X, bf16x8* XH,
                     int4& R, int& R5, int4& B){
        size_t rowoff = (((size_t)((tile << 4) + r)) << 6) + (g << 3);
        const float4* pa = (const float4*)(agg + rowoff);
        A[0] = pa[0]; A[1] = pa[1]; A[2] = pa[8]; A[3] = pa[9];
        if constexpr (XBF){
            const bf16x8* px = (const bf16x8*)(xbf + rowoff);
            XH[0] = px[0]; XH[1] = px[4];
        } else {
            const float4* px = (const float4*)(xf + rowoff);
            X[0] = px[0]; X[1] = px[1]; X[2] = px[8]; X[3] = px[9];
        }
        if (AFF){
            int nb = (tile << 4) + (g << 2);
            R  = *(const int4*)(rs + nb);
            R5 = rs[nb + 4];
            B  = *(const int4*)(batch + nb);
        }
    };

    auto POOL = [&](int gr, float hv){
        int lg = gr - gbase;
        if (lg < 8) atomicAdd(&sS[(lg << 6) + j], hv);
        else        atomicAdd(&S[(gr << 6) + j], hv);
    };

    auto COMPUTE = [&](int tile, const float4* A, const float4* X, const bf16x8* XH,
                       const int4& R, int R5, const int4& B){
        bf16x8 ah0, al0, ah1, al1;
        split8(A[0], A[1], ah0, al0);
        split8(A[2], A[3], ah1, al1);
        f32x4 accA = {0.f, 0.f, 0.f, 0.f};
        f32x4 accX = {0.f, 0.f, 0.f, 0.f};
        accA = __builtin_amdgcn_mfma_f32_16x16x32_bf16(ah0, wlh[0], accA, 0, 0, 0);
        accA = __builtin_amdgcn_mfma_f32_16x16x32_bf16(ah0, wll[0], accA, 0, 0, 0);
        accA = __builtin_amdgcn_mfma_f32_16x16x32_bf16(al0, wlh[0], accA, 0, 0, 0);
        accA = __builtin_amdgcn_mfma_f32_16x16x32_bf16(ah1, wlh[1], accA, 0, 0, 0);
        accA = __builtin_amdgcn_mfma_f32_16x16x32_bf16(ah1, wll[1], accA, 0, 0, 0);
        accA = __builtin_amdgcn_mfma_f32_16x16x32_bf16(al1, wlh[1], accA, 0, 0, 0);
        if constexpr (XBF){
            accX = __builtin_amdgcn_mfma_f32_16x16x32_bf16(XH[0], wrh[0], accX, 0, 0, 0);
            accX = __builtin_amdgcn_mfma_f32_16x16x32_bf16(XH[0], wrl[0], accX, 0, 0, 0);
            accX = __builtin_amdgcn_mfma_f32_16x16x32_bf16(XH[1], wrh[1], accX, 0, 0, 0);
            accX = __builtin_amdgcn_mfma_f32_16x16x32_bf16(XH[1], wrl[1], accX, 0, 0, 0);
        } else {
            bf16x8 xh0, xl0, xh1, xl1;
            split8(X[0], X[1], xh0, xl0);
            split8(X[2], X[3], xh1, xl1);
            accX = __builtin_amdgcn_mfma_f32_16x16x32_bf16(xh0, wrh[0], accX, 0, 0, 0);
            accX = __builtin_amdgcn_mfma_f32_16x16x32_bf16(xh0, wrl[0], accX, 0, 0, 0);
            accX = __builtin_amdgcn_mfma_f32_16x16x32_bf16(xl0, wrh[0], accX, 0, 0, 0);
            accX = __builtin_amdgcn_mfma_f32_16x16x32_bf16(xh1, wrh[1], accX, 0, 0, 0);
            accX = __builtin_amdgcn_mfma_f32_16x16x32_bf16(xh1, wrl[1], accX, 0, 0, 0);
            accX = __builtin_amdgcn_mfma_f32_16x16x32_bf16(xl1, wrh[1], accX, 0, 0, 0);
        }

        int nb = (tile << 4) + (g << 2);
        if (AFF){
            float hv;
            hv = accA[0] + accX[0] + bb + ((R.y - R.x) > 0 ? bd : 0.f);
            hv = leaky(hv); bs += hv; bq += hv*hv; POOL(B.x, hv);
            hv = accA[1] + accX[1] + bb + ((R.z - R.y) > 0 ? bd : 0.f);
            hv = leaky(hv); bs += hv; bq += hv*hv; POOL(B.y, hv);
            hv = accA[2] + accX[2] + bb + ((R.w - R.z) > 0 ? bd : 0.f);
            hv = leaky(hv); bs += hv; bq += hv*hv; POOL(B.z, hv);
            hv = accA[3] + accX[3] + bb + ((R5 - R.w) > 0 ? bd : 0.f);
            hv = leaky(hv); bs += hv; bq += hv*hv; POOL(B.w, hv);
        } else {
            #pragma unroll
            for (int q = 0; q < 4; ++q){
                float hv = leaky(accA[q] + accX[q] + bb);
                unsigned short h16 = f2bf(hv);
                float hr = bf2f(h16);
                hout[((size_t)(nb + q) << 6) + j] = h16;
                bs += hr; bq += hr*hr;
            }
        }
    };

    float4 Aa[4], Xa[4], Ab[4], Xb[4];
    bf16x8 XHa[2], XHb[2];
    int4 Ra = {0,0,0,0}, Rb = {0,0,0,0}, Ba = {0,0,0,0}, Bb = {0,0,0,0};
    int R5a = 0, R5b = 0;

    LOADT(c0, Aa, Xa, XHa, Ra, R5a, Ba);
    for (int c = c0; c < cend; c += 2){
        if (c + 1 < cend) LOADT(c + 1, Ab, Xb, XHb, Rb, R5b, Bb);
        COMPUTE(c, Aa, Xa, XHa, Ra, R5a, Ba);
        if (c + 2 < cend) LOADT(c + 2, Aa, Xa, XHa, Ra, R5a, Ba);
        if (c + 1 < cend) COMPUTE(c + 1, Ab, Xb, XHb, Rb, R5b, Bb);
    }

    bs += __shfl_xor(bs, 16, 64); bs += __shfl_xor(bs, 32, 64);
    bq += __shfl_xor(bq, 16, 64); bq += __shfl_xor(bq, 32, 64);
    if (lane < 16){
        float* bp = bnpart + ((blockIdx.x & 31) * 128);
        atomicAdd(&bp[(jt << 4) + lane], bs);
        atomicAdd(&bp[64 + (jt << 4) + lane], bq);
    }

    if (AFF){
        __syncthreads();
        int sp = min(span, 8);
        for (int i = t; i < (sp << 6); i += 256){
            float v = sS[i];
            if (v != 0.f) atomicAdd(&S[((gbase + (i >> 6)) << 6) + (i & 63)], v);
        }
    }
}

// ============ BN finalize: reduce 32 partial slots; optionally fold next-layer biases ======
template<bool FOLD>
__global__ __launch_bounds__(64) void k_bnfin(
    const float* __restrict__ bnpart,
    const float* __restrict__ gamma, const float* __restrict__ beta,
    const float* __restrict__ Wl_nx, const float* __restrict__ Wr_nx,
    const float* __restrict__ bl_nx,
    float* __restrict__ scale, float* __restrict__ shift,
    float* __restrict__ bbias, float* __restrict__ bdelta)
{
    __shared__ float ssh[64];
    int j = threadIdx.x;
    float s = 0.f, q = 0.f;
    #pragma unroll 8
    for (int i = 0; i < 32; ++i){
        s += bnpart[i*128 + j];
        q += bnpart[i*128 + 64 + j];
    }
    float mu  = s * (1.0f/N_NODES);
    float var = q * (1.0f/N_NODES) - mu*mu;
    float sc  = gamma[j] * rsqrtf(var + EPSV);
    float sh  = beta[j] - mu*sc;
    scale[j] = sc; shift[j] = sh;
    if (FOLD){
        ssh[j] = sh;
        __syncthreads();
        float bbv = bl_nx[j], bdv = 0.f;
        #pragma unroll 8
        for (int k = 0; k < 64; ++k){
            bbv += ssh[k] * Wr_nx[(k << 6) + j];
            bdv += ssh[k] * Wl_nx[(k << 6) + j];
        }
        bbias[j] = bbv; bdelta[j] = bdv;
    }
}

// ============ final MLP (pool finalize fused): one block per graph ============
__global__ __launch_bounds__(256) void k_mlp(
    const float* __restrict__ S, const int* __restrict__ batch,
    const float* __restrict__ scale, const float* __restrict__ shift,
    const float* __restrict__ gf,
    const float* __restrict__ Wm0, const float* __restrict__ bm0,
    const float* __restrict__ Wm1, const float* __restrict__ bm1,
    const float* __restrict__ Wm2, const float* __restrict__ bm2,
    float* __restrict__ out)
{
    __shared__ int seg[2];
    __shared__ float z[128];
    __shared__ float h1[256];
    __shared__ float h2[128];
    int g = blockIdx.x, t = threadIdx.x;
    if (t < 2){
        int target = g + t;
        int lo = 0, hi = N_NODES;
        while (lo < hi){ int mid = (lo+hi)>>1; if (batch[mid] < target) lo = mid+1; else hi = mid; }
        seg[t] = lo;
    }
    __syncthreads();
    float cnt = (float)(seg[1] - seg[0]);
    if (t < 64)
        z[t] = (scale[t]*S[(g<<6)+t] + cnt*shift[t]) / fmaxf(cnt, 1.f);
    else if (t < 128)
        z[t] = gf[g*64 + (t-64)];
    __syncthreads();
    float acc = bm0[t];
    #pragma unroll 8
    for (int k = 0; k < 128; ++k) acc += z[k]*Wm0[k*256 + t];
    h1[t] = leaky(acc);
    __syncthreads();
    if (t < 128){
        float a = bm1[t];
        #pragma unroll 8
        for (int k = 0; k < 256; ++k) a += h1[k]*Wm1[k*128 + t];
        h2[t] = leaky(a);
    }
    __syncthreads();
    if (t < 2){
        float a = bm2[t];
        for (int k = 0; k < 128; ++k) a += h2[k]*Wm2[k*2 + t];
        out[g*2 + t] = a;
    }
}

extern "C" void kernel_launch(void* const* d_in, const int* in_sizes, int n_in,
                              void* d_out, int out_size, void* d_ws, size_t ws_size,
                              hipStream_t stream) {
    const float* x     = (const float*)d_in[0];
    const int*   ei    = (const int*)d_in[1];
    const float* gf    = (const float*)d_in[2];
    const int*   batch = (const int*)d_in[3];
    const float* Wl0 = (const float*)d_in[4];
    const float* bl0 = (const float*)d_in[5];
    const float* Wr0 = (const float*)d_in[6];
    const float* g0  = (const float*)d_in[7];
    const float* b0  = (const float*)d_in[8];
    const float* Wl1 = (const float*)d_in[9];
    const float* bl1 = (const float*)d_in[10];
    const float* Wr1 = (const float*)d_in[11];
    const float* g1  = (const float*)d_in[12];
    const float* b1  = (const float*)d_in[13];
    const float* Wm0 = (const float*)d_in[14];
    const float* bm0 = (const float*)d_in[15];
    const float* Wm1 = (const float*)d_in[16];
    const float* bm1 = (const float*)d_in[17];
    const float* Wm2 = (const float*)d_in[18];
    const float* bm2 = (const float*)d_in[19];

    // ---- workspace ----
    int*   bhist  = (int*)d_ws;                      // [NB]
    int*   boff   = bhist + NB;                      // [NB+1]
    int*   cur    = boff + NB + 1;                   // [NB]
    int*   packed = (int*)d_ws + 2348;               // [E]
    int*   rs     = packed + N_EDGES;                // [N+1] (pad 100004)
    int*   col    = rs + 100004;                     // [E]
    unsigned short* xbf  = (unsigned short*)(col + N_EDGES);  // [N*64] bf16 x
    unsigned short* h1bf = xbf + (size_t)N_NODES*FDIM;        // [N*64] bf16 h1
    float* bufA   = (float*)(h1bf + (size_t)N_NODES*FDIM);    // [N,64] fp32 agg
    float* bnpart = bufA + (size_t)N_NODES*FDIM;     // [32*128]
    float* S      = bnpart + 4096;                   // [128*64]
    float* scale0 = S + N_GRAPHS*FDIM;
    float* shift0 = scale0 + 64;
    float* scale1 = scale0 + 128;
    float* shift1 = scale0 + 192;
    float* bbias  = scale0 + 256;
    float* bdelta = scale0 + 320;

    const int* srcp = ei;
    const int* dstp = ei + N_EDGES;

    // ---- bucketed CSR build + x conversion ----
    hipMemsetAsync(bhist, 0, NB*sizeof(int), stream);
    k_cvt<<<(N_NODES*FDIM/4 + 255)/256, 256, 0, stream>>>(x, xbf);
    k_bh<<<PART_BLOCKS, 256, 0, stream>>>(dstp, bhist);
    k_bscan<<<1, 256, 0, stream>>>(bhist, boff, cur);
    k_part<<<PART_BLOCKS, 256, 0, stream>>>(srcp, dstp, cur, packed);
    k_sort<<<NB, 256, 0, stream>>>(packed, boff, rs, col);

    // ---- layer 1 ----
    hipMemsetAsync(bnpart, 0, 4096*sizeof(float), stream);
    k_agg<<<2048, 256, 0, stream>>>(xbf, rs, col, bufA);
    k_gemm<false, false><<<GEMM_BLOCKS, 256, 0, stream>>>(
        bufA, x, nullptr, h1bf, rs, batch,
        Wl0, Wr0, nullptr, bl0, nullptr, bnpart, nullptr);
    k_bnfin<true><<<1, 64, 0, stream>>>(bnpart, g0, b0, Wl1, Wr1, bl1,
                                        scale0, shift0, bbias, bdelta);

    // ---- layer 2 (h2 never materialized; pooling fused) ----
    hipMemsetAsync(bnpart, 0, (4096 + N_GRAPHS*FDIM)*sizeof(float), stream);
    k_agg<<<2048, 256, 0, stream>>>(h1bf, rs, col, bufA);
    k_gemm<true, true><<<GEMM_BLOCKS, 256, 0, stream>>>(
        bufA, nullptr, h1bf, nullptr, rs, batch,
        Wl1, Wr1, scale0, bbias, bdelta, bnpart, S);
    k_bnfin<false><<<1, 64, 0, stream>>>(bnpart, g1, b1, nullptr, nullptr, nullptr,
                                         scale1, shift1, nullptr, nullptr);

    // ---- pooling finalize + MLP ----
    k_mlp<<<N_GRAPHS, 256, 0, stream>>>(S, batch, scale1, shift1, gf,
                                        Wm0, bm0, Wm1, bm1, Wm2, bm2, (float*)d_out);
}